// Round 2
// baseline (515.032 us; speedup 1.0000x reference)
//
#include <hip/hip_runtime.h>
#include <hip/hip_bf16.h>
#include <math.h>

#define DEVINL __device__ __forceinline__

typedef __attribute__((ext_vector_type(4))) float f32x4;
typedef __attribute__((ext_vector_type(8))) short bf16x8;

constexpr int BATCH = 2;
constexpr int SEQ   = 2048;
constexpr int DIM   = 1024;
constexpr int NH    = 16;
constexpr int KHD   = 64;    // key head dim
constexpr int VHD   = 128;   // value head dim
constexpr int DV    = 2048;  // D * VF
constexpr int MROWS = BATCH * SEQ;      // 4096
constexpr int N1    = DIM + DIM + DV + DV; // 6144

DEVINL unsigned short f2bf(float f) {
    union { float f; unsigned int u; } c; c.f = f;
    unsigned int u = c.u;
    u += 0x7FFFu + ((u >> 16) & 1u);
    return (unsigned short)(u >> 16);
}
DEVINL float bf2f(unsigned short h) {
    union { unsigned int u; float f; } c; c.u = ((unsigned int)h) << 16;
    return c.f;
}
DEVINL f32x4 mfma16(bf16x8 a, bf16x8 b, f32x4 c) {
    return __builtin_amdgcn_mfma_f32_16x16x32_bf16(a, b, c, 0, 0, 0);
}

// ---------------- weight transpose + bf16 convert: src KxN f32 -> dst NxK bf16
__global__ __launch_bounds__(256) void transpose_cvt(const float* __restrict__ src,
                                                     unsigned short* __restrict__ dst,
                                                     int K, int N) {
    __shared__ float t[32][33];
    int bx = blockIdx.x * 32;  // N dim
    int by = blockIdx.y * 32;  // K dim
    int x = threadIdx.x, y = threadIdx.y;  // (32, 8)
    #pragma unroll
    for (int i = 0; i < 32; i += 8) t[y + i][x] = src[(by + y + i) * N + bx + x];
    __syncthreads();
    #pragma unroll
    for (int i = 0; i < 32; i += 8) dst[(bx + y + i) * K + by + x] = f2bf(t[x][y + i]);
}

__global__ void bias_concat(const float* __restrict__ bq, const float* __restrict__ bk,
                            const float* __restrict__ bv, const float* __restrict__ bg,
                            float* __restrict__ ball) {
    int t = blockIdx.x * 256 + threadIdx.x;
    float v;
    if (t < 1024) v = bq[t];
    else if (t < 2048) v = bk[t - 1024];
    else if (t < 4096) v = bv[t - 2048];
    else v = bg[t - 4096];
    ball[t] = v;
}

__global__ void rope_kernel(float* __restrict__ rsin, float* __restrict__ rcos) {
    int t = blockIdx.x * 256 + threadIdx.x;  // 0..65535
    int s = t >> 5, i = t & 31;
    float ang = powf(10000.f, -(float)i / 31.f);
    float th = (float)s * ang;
    float sv, cv;
    sincosf(th, &sv, &cv);
    rsin[s * 64 + 2 * i] = sv; rsin[s * 64 + 2 * i + 1] = sv;
    rcos[s * 64 + 2 * i] = cv; rcos[s * 64 + 2 * i + 1] = cv;
}

// ---------------- LayerNorm of x -> bf16
__global__ __launch_bounds__(256) void ln_x_kernel(const float* __restrict__ x,
                                                   const float* __restrict__ g,
                                                   const float* __restrict__ b,
                                                   unsigned short* __restrict__ xn) {
    int row = blockIdx.x;
    int t = threadIdx.x;
    const float4 v = *(const float4*)(x + row * 1024 + t * 4);
    float s1 = v.x + v.y + v.z + v.w;
    float s2 = v.x * v.x + v.y * v.y + v.z * v.z + v.w * v.w;
    #pragma unroll
    for (int off = 1; off < 64; off <<= 1) { s1 += __shfl_xor(s1, off); s2 += __shfl_xor(s2, off); }
    __shared__ float red[8];
    int wave = t >> 6, lane = t & 63;
    if (lane == 0) { red[wave] = s1; red[4 + wave] = s2; }
    __syncthreads();
    s1 = red[0] + red[1] + red[2] + red[3];
    s2 = red[4] + red[5] + red[6] + red[7];
    float mean = s1 * (1.f / 1024.f);
    float rstd = rsqrtf(s2 * (1.f / 1024.f) - mean * mean + 1e-5f);
    const float4 gv = *(const float4*)(g + t * 4);
    const float4 bv = *(const float4*)(b + t * 4);
    ushort4 o;
    o.x = f2bf((v.x - mean) * rstd * gv.x + bv.x);
    o.y = f2bf((v.y - mean) * rstd * gv.y + bv.y);
    o.z = f2bf((v.z - mean) * rstd * gv.z + bv.z);
    o.w = f2bf((v.w - mean) * rstd * gv.w + bv.w);
    *(ushort4*)&xn[row * 1024 + t * 4] = o;
}

// ---------------- GEMM1: xn[4096x1024] @ WT[6144x1024]^T + epilogue
// epilogue: bias, k-scale, RoPE (q,k), silu (gate), scatter to head layouts
__global__ __launch_bounds__(256) void gemm1_kernel(
    const unsigned short* __restrict__ Abf, const unsigned short* __restrict__ WT,
    const float* __restrict__ ball, const float* __restrict__ rsin,
    const float* __restrict__ rcos, unsigned short* __restrict__ qb,
    unsigned short* __restrict__ kb, unsigned short* __restrict__ vb,
    unsigned short* __restrict__ gb) {
    __shared__ unsigned short As[128 * 32];
    __shared__ unsigned short Bs[128 * 32];
    const int tid = threadIdx.x;
    const int lane = tid & 63, wave = tid >> 6;
    const int wr = wave >> 1, wc = wave & 1;
    const int m0 = blockIdx.y * 128, n0 = blockIdx.x * 128;
    const int l15 = lane & 15, lg = lane >> 4;

    f32x4 acc[4][4];
    #pragma unroll
    for (int i = 0; i < 4; i++)
        #pragma unroll
        for (int j = 0; j < 4; j++) acc[i][j] = (f32x4){0.f, 0.f, 0.f, 0.f};

    const int offA = tid * 8;
    const int rowA = offA >> 5, kA = offA & 31;

    for (int k0 = 0; k0 < 1024; k0 += 32) {
        uint4 ra0 = *(const uint4*)(Abf + (m0 + rowA) * 1024 + k0 + kA);
        uint4 ra1 = *(const uint4*)(Abf + (m0 + rowA + 64) * 1024 + k0 + kA);
        uint4 rb0 = *(const uint4*)(WT + (n0 + rowA) * 1024 + k0 + kA);
        uint4 rb1 = *(const uint4*)(WT + (n0 + rowA + 64) * 1024 + k0 + kA);
        __syncthreads();
        *(uint4*)&As[offA] = ra0; *(uint4*)&As[offA + 2048] = ra1;
        *(uint4*)&Bs[offA] = rb0; *(uint4*)&Bs[offA + 2048] = rb1;
        __syncthreads();
        bf16x8 af[4], bfr[4];
        #pragma unroll
        for (int m = 0; m < 4; m++) af[m] = *(const bf16x8*)&As[(64 * wr + 16 * m + l15) * 32 + 8 * lg];
        #pragma unroll
        for (int n = 0; n < 4; n++) bfr[n] = *(const bf16x8*)&Bs[(64 * wc + 16 * n + l15) * 32 + 8 * lg];
        #pragma unroll
        for (int m = 0; m < 4; m++)
            #pragma unroll
            for (int n = 0; n < 4; n++) acc[m][n] = mfma16(af[m], bfr[n], acc[m][n]);
    }

    const int rowbase = m0 + 64 * wr + 4 * lg;  // + 16*m + r
    const int colbase = n0 + 64 * wc + l15;     // + 16*n
    #pragma unroll
    for (int n = 0; n < 4; n++) {
        int col = colbase + 16 * n;
        float bias = ball[col];
        if (col < 2048) {                       // q or k with RoPE
            bool isK = col >= 1024;
            int c = col & 1023;
            int hh = c >> 6, d = c & 63;
            unsigned short* dst = isK ? kb : qb;
            #pragma unroll
            for (int m = 0; m < 4; m++) {
                #pragma unroll
                for (int r = 0; r < 4; r++) {
                    int row = rowbase + 16 * m + r;
                    int s = row & (SEQ - 1);
                    int bsel = row >> 11;
                    float v = acc[m][n][r] + bias;
                    if (isK) v *= 0.125f;
                    float cs = rcos[s * 64 + d], sn = rsin[s * 64 + d];
                    float pv = __shfl_xor(v, 1);
                    float res = ((d & 1) == 0) ? (v * cs - pv * sn) : (v * cs + pv * sn);
                    float pr = __shfl_xor(res, 1);
                    if ((lane & 1) == 0) {
                        unsigned int pk = (unsigned int)f2bf(res) | ((unsigned int)f2bf(pr) << 16);
                        *(unsigned int*)&dst[(((bsel * NH + hh) * SEQ) + s) * KHD + d] = pk;
                    }
                }
            }
        } else if (col < 4096) {                // v -> transposed (b,h,vd,s)
            int c = col - 2048;
            int hh = c >> 7, vd = c & 127;
            #pragma unroll
            for (int m = 0; m < 4; m++) {
                int row = rowbase + 16 * m;
                int s = row & (SEQ - 1);
                int bsel = row >> 11;
                ushort4 u4;
                u4.x = f2bf(acc[m][n][0] + bias);
                u4.y = f2bf(acc[m][n][1] + bias);
                u4.z = f2bf(acc[m][n][2] + bias);
                u4.w = f2bf(acc[m][n][3] + bias);
                *(ushort4*)&vb[(((bsel * NH + hh) * VHD) + vd) * SEQ + s] = u4;
            }
        } else {                                // gate -> silu, (b,s,2048)
            int c = col - 4096;
            #pragma unroll
            for (int m = 0; m < 4; m++) {
                #pragma unroll
                for (int r = 0; r < 4; r++) {
                    int row = rowbase + 16 * m + r;
                    int s = row & (SEQ - 1);
                    int bsel = row >> 11;
                    float v = acc[m][n][r] + bias;
                    float sg = v / (1.f + expf(-v));
                    float pr = __shfl_xor(sg, 1);
                    if ((lane & 1) == 0) {
                        unsigned int pk = (unsigned int)f2bf(sg) | ((unsigned int)f2bf(pr) << 16);
                        *(unsigned int*)&gb[((bsel * SEQ + s) * DV) + c] = pk;
                    }
                }
            }
        }
    }
}

// ---------------- retention: per (b,h,i-tile 64): O = sum_j (QK^T * lambda^(i-j)) V
// then per-row LN over VD, * silu(gate), write z (b,s,2048) bf16
__global__ __launch_bounds__(256) void retention_kernel(
    const unsigned short* __restrict__ qb, const unsigned short* __restrict__ kb,
    const unsigned short* __restrict__ vb, const unsigned short* __restrict__ gb,
    const float* __restrict__ lng, const float* __restrict__ lnb,
    unsigned short* __restrict__ zb) {
    __shared__ unsigned short Qs[64 * 64];
    __shared__ unsigned short Ks[64 * 64];
    __shared__ unsigned short Ps[64 * 64];
    __shared__ unsigned short VsT[128 * 64];
    const int tid = threadIdx.x, lane = tid & 63, wave = tid >> 6;
    const int l15 = lane & 15, lg = lane >> 4;
    const int itile = blockIdx.x, bh = blockIdx.y;
    const int b = bh >> 4, h = bh & 15;
    const int i0 = itile * 64;
    const float dl2 = log1pf(-exp2f(-(float)(5 + h))) * 1.44269504088896f;  // log2(lambda_h)

    {   // stage Q (8KB linear)
        int off = tid * 8;
        const unsigned short* qbase = qb + (bh * SEQ + i0) * KHD;
        *(uint4*)&Qs[off] = *(const uint4*)(qbase + off);
        *(uint4*)&Qs[off + 2048] = *(const uint4*)(qbase + off + 2048);
    }
    __syncthreads();
    bf16x8 aq0 = *(const bf16x8*)&Qs[(16 * wave + l15) * 64 + 8 * lg];
    bf16x8 aq1 = *(const bf16x8*)&Qs[(16 * wave + l15) * 64 + 32 + 8 * lg];

    f32x4 oacc[8];
    #pragma unroll
    for (int n = 0; n < 8; n++) oacc[n] = (f32x4){0.f, 0.f, 0.f, 0.f};

    for (int jt = 0; jt <= itile; ++jt) {
        int j0 = jt * 64;
        __syncthreads();  // protect Ks/VsT while still in use by prior iter
        {
            int off = tid * 8;
            const unsigned short* kbase = kb + (bh * SEQ + j0) * KHD;
            *(uint4*)&Ks[off] = *(const uint4*)(kbase + off);
            *(uint4*)&Ks[off + 2048] = *(const uint4*)(kbase + off + 2048);
            const unsigned short* vbase = vb + bh * VHD * SEQ + j0;
            #pragma unroll
            for (int it = 0; it < 4; ++it) {
                int o = off + it * 2048;
                int vd = o >> 6, jj = o & 63;
                *(uint4*)&VsT[o] = *(const uint4*)(vbase + vd * SEQ + jj);
            }
        }
        __syncthreads();
        // QK^T
        f32x4 pacc[4];
        #pragma unroll
        for (int n = 0; n < 4; n++) pacc[n] = (f32x4){0.f, 0.f, 0.f, 0.f};
        #pragma unroll
        for (int n = 0; n < 4; n++) {
            bf16x8 b0 = *(const bf16x8*)&Ks[(16 * n + l15) * 64 + 8 * lg];
            bf16x8 b1 = *(const bf16x8*)&Ks[(16 * n + l15) * 64 + 32 + 8 * lg];
            pacc[n] = mfma16(aq0, b0, pacc[n]);
            pacc[n] = mfma16(aq1, b1, pacc[n]);
        }
        // decay scale + causal mask + bf16, wave-local Ps rows
        #pragma unroll
        for (int n = 0; n < 4; n++) {
            #pragma unroll
            for (int r = 0; r < 4; r++) {
                int il = 16 * wave + 4 * lg + r;
                int jl = 16 * n + l15;
                int diff = (i0 + il) - (j0 + jl);
                float f = (diff >= 0) ? exp2f((float)diff * dl2) : 0.f;
                Ps[il * 64 + jl] = f2bf(pacc[n][r] * f);
            }
        }
        // PV (Ps rows are wave-local: no barrier needed)
        bf16x8 ap0 = *(const bf16x8*)&Ps[(16 * wave + l15) * 64 + 8 * lg];
        bf16x8 ap1 = *(const bf16x8*)&Ps[(16 * wave + l15) * 64 + 32 + 8 * lg];
        #pragma unroll
        for (int n = 0; n < 8; n++) {
            bf16x8 b0 = *(const bf16x8*)&VsT[(16 * n + l15) * 64 + 8 * lg];
            bf16x8 b1 = *(const bf16x8*)&VsT[(16 * n + l15) * 64 + 32 + 8 * lg];
            oacc[n] = mfma16(ap0, b0, oacc[n]);
            oacc[n] = mfma16(ap1, b1, oacc[n]);
        }
    }

    // epilogue: per-row LN over 128, * silu(gate), store z
    #pragma unroll
    for (int r = 0; r < 4; r++) {
        float s1 = 0.f, s2 = 0.f;
        #pragma unroll
        for (int n = 0; n < 8; n++) { float v = oacc[n][r]; s1 += v; s2 += v * v; }
        #pragma unroll
        for (int off = 1; off < 16; off <<= 1) { s1 += __shfl_xor(s1, off); s2 += __shfl_xor(s2, off); }
        float mean = s1 * (1.f / 128.f);
        float var = s2 * (1.f / 128.f) - mean * mean;
        float rstd = rsqrtf(var + 1e-5f);
        int il = 16 * wave + 4 * lg + r;
        int s = i0 + il;
        int zrow = b * SEQ + s;
        #pragma unroll
        for (int n = 0; n < 8; n++) {
            int col = 16 * n + l15;
            float y = (oacc[n][r] - mean) * rstd * lng[col] + lnb[col];
            float g = bf2f(gb[zrow * DV + h * VHD + col]);
            zb[zrow * DV + h * VHD + col] = f2bf(y * g);
        }
    }
}

// ---------------- GEMM2: z[4096x2048] @ WoT[1024x2048]^T + bo -> out f32
__global__ __launch_bounds__(256) void gemm2_kernel(
    const unsigned short* __restrict__ Z, const unsigned short* __restrict__ WoT,
    const float* __restrict__ bo, float* __restrict__ out) {
    __shared__ unsigned short As[128 * 32];
    __shared__ unsigned short Bs[128 * 32];
    const int tid = threadIdx.x;
    const int lane = tid & 63, wave = tid >> 6;
    const int wr = wave >> 1, wc = wave & 1;
    const int m0 = blockIdx.y * 128, n0 = blockIdx.x * 128;
    const int l15 = lane & 15, lg = lane >> 4;

    f32x4 acc[4][4];
    #pragma unroll
    for (int i = 0; i < 4; i++)
        #pragma unroll
        for (int j = 0; j < 4; j++) acc[i][j] = (f32x4){0.f, 0.f, 0.f, 0.f};

    const int offA = tid * 8;
    const int rowA = offA >> 5, kA = offA & 31;

    for (int k0 = 0; k0 < 2048; k0 += 32) {
        uint4 ra0 = *(const uint4*)(Z + (m0 + rowA) * 2048 + k0 + kA);
        uint4 ra1 = *(const uint4*)(Z + (m0 + rowA + 64) * 2048 + k0 + kA);
        uint4 rb0 = *(const uint4*)(WoT + (n0 + rowA) * 2048 + k0 + kA);
        uint4 rb1 = *(const uint4*)(WoT + (n0 + rowA + 64) * 2048 + k0 + kA);
        __syncthreads();
        *(uint4*)&As[offA] = ra0; *(uint4*)&As[offA + 2048] = ra1;
        *(uint4*)&Bs[offA] = rb0; *(uint4*)&Bs[offA + 2048] = rb1;
        __syncthreads();
        bf16x8 af[4], bfr[4];
        #pragma unroll
        for (int m = 0; m < 4; m++) af[m] = *(const bf16x8*)&As[(64 * wr + 16 * m + l15) * 32 + 8 * lg];
        #pragma unroll
        for (int n = 0; n < 4; n++) bfr[n] = *(const bf16x8*)&Bs[(64 * wc + 16 * n + l15) * 32 + 8 * lg];
        #pragma unroll
        for (int m = 0; m < 4; m++)
            #pragma unroll
            for (int n = 0; n < 4; n++) acc[m][n] = mfma16(af[m], bfr[n], acc[m][n]);
    }

    #pragma unroll
    for (int n = 0; n < 4; n++) {
        int col = n0 + 64 * wc + 16 * n + l15;
        float bias = bo[col];
        #pragma unroll
        for (int m = 0; m < 4; m++) {
            #pragma unroll
            for (int r = 0; r < 4; r++) {
                int row = m0 + 64 * wr + 16 * m + 4 * lg + r;
                out[row * 1024 + col] = acc[m][n][r] + bias;
            }
        }
    }
}

extern "C" void kernel_launch(void* const* d_in, const int* in_sizes, int n_in,
                              void* d_out, int out_size, void* d_ws, size_t ws_size,
                              hipStream_t stream) {
    (void)in_sizes; (void)n_in; (void)out_size; (void)ws_size;
    const float* x   = (const float*)d_in[0];
    const float* Wq  = (const float*)d_in[2];
    const float* bq  = (const float*)d_in[3];
    const float* Wk  = (const float*)d_in[4];
    const float* bk  = (const float*)d_in[5];
    const float* Wv  = (const float*)d_in[6];
    const float* bv  = (const float*)d_in[7];
    const float* Wg  = (const float*)d_in[8];
    const float* bg  = (const float*)d_in[9];
    const float* Wo  = (const float*)d_in[10];
    const float* bo  = (const float*)d_in[11];
    const float* lpg = (const float*)d_in[12];
    const float* lpb = (const float*)d_in[13];
    const float* lhg = (const float*)d_in[14];
    const float* lhb = (const float*)d_in[15];

    char* w = (char*)d_ws;
    auto alloc = [&](size_t bytes) { char* p = w; w += (bytes + 255) & ~(size_t)255; return p; };
    unsigned short* WT   = (unsigned short*)alloc((size_t)N1 * DIM * 2);
    unsigned short* WoT  = (unsigned short*)alloc((size_t)DIM * DV * 2);
    float*          ball = (float*)alloc((size_t)N1 * 4);
    float*          rsin = (float*)alloc((size_t)SEQ * 64 * 4);
    float*          rcos = (float*)alloc((size_t)SEQ * 64 * 4);
    unsigned short* xn   = (unsigned short*)alloc((size_t)MROWS * DIM * 2);
    unsigned short* qb   = (unsigned short*)alloc((size_t)BATCH * NH * SEQ * KHD * 2);
    unsigned short* kb   = (unsigned short*)alloc((size_t)BATCH * NH * SEQ * KHD * 2);
    unsigned short* vb   = (unsigned short*)alloc((size_t)BATCH * NH * VHD * SEQ * 2);
    unsigned short* gb   = (unsigned short*)alloc((size_t)MROWS * DV * 2);
    unsigned short* zb   = (unsigned short*)alloc((size_t)MROWS * DV * 2);

    dim3 tb(32, 8);
    transpose_cvt<<<dim3(32, 32), tb, 0, stream>>>(Wq, WT + 0 * DIM, DIM, DIM);
    transpose_cvt<<<dim3(32, 32), tb, 0, stream>>>(Wk, WT + 1024 * DIM, DIM, DIM);
    transpose_cvt<<<dim3(64, 32), tb, 0, stream>>>(Wv, WT + 2048 * DIM, DIM, DV);
    transpose_cvt<<<dim3(64, 32), tb, 0, stream>>>(Wg, WT + 4096 * DIM, DIM, DV);
    transpose_cvt<<<dim3(32, 64), tb, 0, stream>>>(Wo, WoT, DV, DIM);
    bias_concat<<<24, 256, 0, stream>>>(bq, bk, bv, bg, ball);
    rope_kernel<<<256, 256, 0, stream>>>(rsin, rcos);
    ln_x_kernel<<<MROWS, 256, 0, stream>>>(x, lpg, lpb, xn);
    gemm1_kernel<<<dim3(48, 32), 256, 0, stream>>>(xn, WT, ball, rsin, rcos, qb, kb, vb, gb);
    retention_kernel<<<dim3(32, 32), 256, 0, stream>>>(qb, kb, vb, gb, lhg, lhb, zb);
    gemm2_kernel<<<dim3(8, 32), 256, 0, stream>>>(zb, WoT, bo, (float*)d_out);
}

// Round 6
// 467.090 us; speedup vs baseline: 1.1026x; 1.1026x over previous
//
#include <hip/hip_runtime.h>
#include <hip/hip_bf16.h>
#include <math.h>

#define DEVINL __device__ __forceinline__

typedef __attribute__((ext_vector_type(4))) float f32x4;
typedef __attribute__((ext_vector_type(8))) short bf16x8;

constexpr int BATCH = 2;
constexpr int SEQ   = 2048;
constexpr int DIM   = 1024;
constexpr int NH    = 16;
constexpr int KHD   = 64;    // key head dim
constexpr int VHD   = 128;   // value head dim
constexpr int DV    = 2048;  // D * VF
constexpr int MROWS = BATCH * SEQ;      // 4096
constexpr int N1    = DIM + DIM + DV + DV; // 6144

DEVINL unsigned short f2bf(float f) {
    union { float f; unsigned int u; } c; c.f = f;
    unsigned int u = c.u;
    u += 0x7FFFu + ((u >> 16) & 1u);
    return (unsigned short)(u >> 16);
}
DEVINL float bf2f(unsigned short h) {
    union { unsigned int u; float f; } c; c.u = ((unsigned int)h) << 16;
    return c.f;
}
DEVINL f32x4 mfma16(bf16x8 a, bf16x8 b, f32x4 c) {
    return __builtin_amdgcn_mfma_f32_16x16x32_bf16(a, b, c, 0, 0, 0);
}
// async global->LDS, 16B per lane; l must be the wave-uniform base (lane*16B implicit)
DEVINL void gload16(const unsigned short* g, unsigned short* l) {
    __builtin_amdgcn_global_load_lds(
        (const __attribute__((address_space(1))) unsigned int*)g,
        (__attribute__((address_space(3))) unsigned int*)l, 16, 0, 0);
}
// XOR swizzle for 128B-row LDS tiles: chunk slot = chunkidx ^ (row&7)
DEVINL int swz(int row, int colb) { return row * 128 + (colb ^ ((row & 7) << 4)); }

// ---------------- weight transpose + bf16 convert: src KxN f32 -> dst NxK bf16
__global__ __launch_bounds__(256) void transpose_cvt(const float* __restrict__ src,
                                                     unsigned short* __restrict__ dst,
                                                     int K, int N) {
    __shared__ float t[32][33];
    int bx = blockIdx.x * 32;  // N dim
    int by = blockIdx.y * 32;  // K dim
    int x = threadIdx.x, y = threadIdx.y;  // (32, 8)
    #pragma unroll
    for (int i = 0; i < 32; i += 8) t[y + i][x] = src[(by + y + i) * N + bx + x];
    __syncthreads();
    #pragma unroll
    for (int i = 0; i < 32; i += 8) dst[(bx + y + i) * K + by + x] = f2bf(t[x][y + i]);
}

__global__ void bias_concat(const float* __restrict__ bq, const float* __restrict__ bk,
                            const float* __restrict__ bv, const float* __restrict__ bg,
                            float* __restrict__ ball) {
    int t = blockIdx.x * 256 + threadIdx.x;
    float v;
    if (t < 1024) v = bq[t];
    else if (t < 2048) v = bk[t - 1024];
    else if (t < 4096) v = bv[t - 2048];
    else v = bg[t - 4096];
    ball[t] = v;
}

__global__ void rope_kernel(float* __restrict__ rsin, float* __restrict__ rcos) {
    int t = blockIdx.x * 256 + threadIdx.x;  // 0..65535
    int s = t >> 5, i = t & 31;
    float ang = powf(10000.f, -(float)i / 31.f);
    float th = (float)s * ang;
    float sv, cv;
    sincosf(th, &sv, &cv);
    rsin[s * 64 + 2 * i] = sv; rsin[s * 64 + 2 * i + 1] = sv;
    rcos[s * 64 + 2 * i] = cv; rcos[s * 64 + 2 * i + 1] = cv;
}

// ---------------- LayerNorm of x -> bf16
__global__ __launch_bounds__(256) void ln_x_kernel(const float* __restrict__ x,
                                                   const float* __restrict__ g,
                                                   const float* __restrict__ b,
                                                   unsigned short* __restrict__ xn) {
    int row = blockIdx.x;
    int t = threadIdx.x;
    const float4 v = *(const float4*)(x + row * 1024 + t * 4);
    float s1 = v.x + v.y + v.z + v.w;
    float s2 = v.x * v.x + v.y * v.y + v.z * v.z + v.w * v.w;
    #pragma unroll
    for (int off = 1; off < 64; off <<= 1) { s1 += __shfl_xor(s1, off); s2 += __shfl_xor(s2, off); }
    __shared__ float red[8];
    int wave = t >> 6, lane = t & 63;
    if (lane == 0) { red[wave] = s1; red[4 + wave] = s2; }
    __syncthreads();
    s1 = red[0] + red[1] + red[2] + red[3];
    s2 = red[4] + red[5] + red[6] + red[7];
    float mean = s1 * (1.f / 1024.f);
    float rstd = rsqrtf(s2 * (1.f / 1024.f) - mean * mean + 1e-5f);
    const float4 gv = *(const float4*)(g + t * 4);
    const float4 bv = *(const float4*)(b + t * 4);
    ushort4 o;
    o.x = f2bf((v.x - mean) * rstd * gv.x + bv.x);
    o.y = f2bf((v.y - mean) * rstd * gv.y + bv.y);
    o.z = f2bf((v.z - mean) * rstd * gv.z + bv.z);
    o.w = f2bf((v.w - mean) * rstd * gv.w + bv.w);
    *(ushort4*)&xn[row * 1024 + t * 4] = o;
}

// ---------------- GEMM1: xn[4096x1024] @ WT[6144x1024]^T + epilogue
__global__ __launch_bounds__(256) void gemm1_kernel(
    const unsigned short* __restrict__ Abf, const unsigned short* __restrict__ WT,
    const float* __restrict__ ball, const float* __restrict__ rsin,
    const float* __restrict__ rcos, unsigned short* __restrict__ qb,
    unsigned short* __restrict__ kb, unsigned short* __restrict__ vb,
    unsigned short* __restrict__ gb) {
    __shared__ unsigned short As[128 * 32];
    __shared__ unsigned short Bs[128 * 32];
    const int tid = threadIdx.x;
    const int lane = tid & 63, wave = tid >> 6;
    const int wr = wave >> 1, wc = wave & 1;
    const int m0 = blockIdx.y * 128, n0 = blockIdx.x * 128;
    const int l15 = lane & 15, lg = lane >> 4;

    f32x4 acc[4][4];
    #pragma unroll
    for (int i = 0; i < 4; i++)
        #pragma unroll
        for (int j = 0; j < 4; j++) acc[i][j] = (f32x4){0.f, 0.f, 0.f, 0.f};

    const int rowA = tid >> 2, kA = (tid & 3) * 8;   // lane-linear: LDS byte = tid*16

    for (int k0 = 0; k0 < 1024; k0 += 32) {
        __syncthreads();
        gload16(Abf + (m0 + rowA) * 1024 + k0 + kA, As + (wave << 9));
        gload16(Abf + (m0 + rowA + 64) * 1024 + k0 + kA, As + 2048 + (wave << 9));
        gload16(WT + (n0 + rowA) * 1024 + k0 + kA, Bs + (wave << 9));
        gload16(WT + (n0 + rowA + 64) * 1024 + k0 + kA, Bs + 2048 + (wave << 9));
        __syncthreads();
        bf16x8 af[4], bfr[4];
        #pragma unroll
        for (int m = 0; m < 4; m++) af[m] = *(const bf16x8*)&As[(64 * wr + 16 * m + l15) * 32 + 8 * lg];
        #pragma unroll
        for (int n = 0; n < 4; n++) bfr[n] = *(const bf16x8*)&Bs[(64 * wc + 16 * n + l15) * 32 + 8 * lg];
        #pragma unroll
        for (int m = 0; m < 4; m++)
            #pragma unroll
            for (int n = 0; n < 4; n++) acc[m][n] = mfma16(af[m], bfr[n], acc[m][n]);
    }

    const int rowbase = m0 + 64 * wr + 4 * lg;  // + 16*m + r
    const int colbase = n0 + 64 * wc + l15;     // + 16*n
    #pragma unroll
    for (int n = 0; n < 4; n++) {
        int col = colbase + 16 * n;
        float bias = ball[col];
        if (col < 2048) {                       // q or k with RoPE
            bool isK = col >= 1024;
            int c = col & 1023;
            int hh = c >> 6, d = c & 63;
            unsigned short* dst = isK ? kb : qb;
            #pragma unroll
            for (int m = 0; m < 4; m++) {
                #pragma unroll
                for (int r = 0; r < 4; r++) {
                    int row = rowbase + 16 * m + r;
                    int s = row & (SEQ - 1);
                    int bsel = row >> 11;
                    float v = acc[m][n][r] + bias;
                    if (isK) v *= 0.125f;
                    float cs = rcos[s * 64 + d], sn = rsin[s * 64 + d];
                    float pv = __shfl_xor(v, 1);
                    float res = ((d & 1) == 0) ? (v * cs - pv * sn) : (v * cs + pv * sn);
                    float pr = __shfl_xor(res, 1);
                    if ((lane & 1) == 0) {
                        unsigned int pk = (unsigned int)f2bf(res) | ((unsigned int)f2bf(pr) << 16);
                        *(unsigned int*)&dst[(((bsel * NH + hh) * SEQ) + s) * KHD + d] = pk;
                    }
                }
            }
        } else if (col < 4096) {                // v -> transposed (b,h,vd,s)
            int c = col - 2048;
            int hh = c >> 7, vd = c & 127;
            #pragma unroll
            for (int m = 0; m < 4; m++) {
                int row = rowbase + 16 * m;
                int s = row & (SEQ - 1);
                int bsel = row >> 11;
                ushort4 u4;
                u4.x = f2bf(acc[m][n][0] + bias);
                u4.y = f2bf(acc[m][n][1] + bias);
                u4.z = f2bf(acc[m][n][2] + bias);
                u4.w = f2bf(acc[m][n][3] + bias);
                *(ushort4*)&vb[(((bsel * NH + hh) * VHD) + vd) * SEQ + s] = u4;
            }
        } else {                                // gate -> silu, (b,s,2048)
            int c = col - 4096;
            #pragma unroll
            for (int m = 0; m < 4; m++) {
                #pragma unroll
                for (int r = 0; r < 4; r++) {
                    int row = rowbase + 16 * m + r;
                    int s = row & (SEQ - 1);
                    int bsel = row >> 11;
                    float v = acc[m][n][r] + bias;
                    float sg = v / (1.f + expf(-v));
                    float pr = __shfl_xor(sg, 1);
                    if ((lane & 1) == 0) {
                        unsigned int pk = (unsigned int)f2bf(sg) | ((unsigned int)f2bf(pr) << 16);
                        *(unsigned int*)&gb[((bsel * SEQ + s) * DV) + c] = pk;
                    }
                }
            }
        }
    }
}

// ---------------- retention: per (b,h,i-tile 64): O = sum_j (QK^T * lambda^(i-j)) V
// LDS tiles XOR-swizzled (T2); K/V async reg-staged (T14); longest-first order.
__global__ __launch_bounds__(256) void retention_kernel(
    const unsigned short* __restrict__ qb, const unsigned short* __restrict__ kb,
    const unsigned short* __restrict__ vb, const unsigned short* __restrict__ gb,
    const float* __restrict__ lng, const float* __restrict__ lnb,
    unsigned short* __restrict__ zb) {
    __shared__ char Qb[64 * 128];
    __shared__ char Kb[64 * 128];
    __shared__ char Pb[64 * 128];
    __shared__ char Vb[128 * 128];
    const int tid = threadIdx.x, lane = tid & 63, wave = tid >> 6;
    const int l15 = lane & 15, lg = lane >> 4;
    const int itile = gridDim.x - 1 - blockIdx.x;   // longest-first
    const int bh = blockIdx.y;
    const int b = bh >> 4, h = bh & 15;
    const int i0 = itile * 64;
    const float dl2 = log1pf(-exp2f(-(float)(5 + h))) * 1.44269504088896f;  // log2(lambda_h)

    const int srow = tid >> 3, scolb = (tid & 7) * 16;   // staging row/col (16B chunks)

    {   // stage Q (swizzled)
        const unsigned short* qbase = qb + (bh * SEQ + i0) * KHD;
        uint4 q0 = *(const uint4*)(qbase + tid * 8);
        uint4 q1 = *(const uint4*)(qbase + tid * 8 + 2048);
        *(uint4*)(Qb + swz(srow, scolb)) = q0;
        *(uint4*)(Qb + swz(srow + 32, scolb)) = q1;
    }
    __syncthreads();
    bf16x8 aq0 = *(const bf16x8*)(Qb + swz(16 * wave + l15, 16 * lg));
    bf16x8 aq1 = *(const bf16x8*)(Qb + swz(16 * wave + l15, 64 + 16 * lg));

    // decay bases: lambda^(il-jl), il = 16w+4lg+r, jl = 16n+l15
    float base[4][4], based[4][4];
    #pragma unroll
    for (int n = 0; n < 4; n++)
        #pragma unroll
        for (int r = 0; r < 4; r++) {
            int d = (16 * wave + 4 * lg + r) - (16 * n + l15);
            float e = exp2f((float)d * dl2);
            base[n][r] = e;
            based[n][r] = (d >= 0) ? e : 0.f;
        }

    f32x4 oacc[8];
    #pragma unroll
    for (int n = 0; n < 8; n++) oacc[n] = (f32x4){0.f, 0.f, 0.f, 0.f};

    // K/V register staging (T14)
    uint4 kr0, kr1, vrg[4];
    const unsigned short* kbh = kb + bh * SEQ * KHD;
    const unsigned short* vbh = vb + bh * VHD * SEQ;
    {
        kr0 = *(const uint4*)(kbh + tid * 8);
        kr1 = *(const uint4*)(kbh + tid * 8 + 2048);
        #pragma unroll
        for (int it = 0; it < 4; ++it) {
            int o = tid * 8 + it * 2048;
            vrg[it] = *(const uint4*)(vbh + (o >> 6) * SEQ + (o & 63));
        }
    }

    for (int jt = 0; jt <= itile; ++jt) {
        __syncthreads();   // LDS free (prev compute done)
        *(uint4*)(Kb + swz(srow, scolb)) = kr0;
        *(uint4*)(Kb + swz(srow + 32, scolb)) = kr1;
        #pragma unroll
        for (int it = 0; it < 4; ++it) *(uint4*)(Vb + swz(srow + 32 * it, scolb)) = vrg[it];
        __syncthreads();
        if (jt < itile) {   // issue next-tile loads; latency hides under compute
            int j0 = (jt + 1) * 64;
            kr0 = *(const uint4*)(kbh + j0 * KHD + tid * 8);
            kr1 = *(const uint4*)(kbh + j0 * KHD + tid * 8 + 2048);
            #pragma unroll
            for (int it = 0; it < 4; ++it) {
                int o = tid * 8 + it * 2048;
                vrg[it] = *(const uint4*)(vbh + (o >> 6) * SEQ + (o & 63) + j0);
            }
        }
        // QK^T
        f32x4 pacc[4];
        #pragma unroll
        for (int n = 0; n < 4; n++) pacc[n] = (f32x4){0.f, 0.f, 0.f, 0.f};
        #pragma unroll
        for (int n = 0; n < 4; n++) {
            bf16x8 b0 = *(const bf16x8*)(Kb + swz(16 * n + l15, 16 * lg));
            bf16x8 b1 = *(const bf16x8*)(Kb + swz(16 * n + l15, 64 + 16 * lg));
            pacc[n] = mfma16(aq0, b0, pacc[n]);
            pacc[n] = mfma16(aq1, b1, pacc[n]);
        }
        // decay scale + causal mask + bf16, wave-local Ps rows
        bool diag = (jt == itile);
        float fac = diag ? 1.f : exp2f((float)(64 * (itile - jt)) * dl2);
        #pragma unroll
        for (int n = 0; n < 4; n++) {
            #pragma unroll
            for (int r = 0; r < 4; r++) {
                int il = 16 * wave + 4 * lg + r;
                int jl = 16 * n + l15;
                float fnr = diag ? based[n][r] : fac * base[n][r];
                *(unsigned short*)(Pb + swz(il, jl * 2)) = f2bf(pacc[n][r] * fnr);
            }
        }
        // PV (Ps rows are wave-local: no barrier needed)
        bf16x8 ap0 = *(const bf16x8*)(Pb + swz(16 * wave + l15, 16 * lg));
        bf16x8 ap1 = *(const bf16x8*)(Pb + swz(16 * wave + l15, 64 + 16 * lg));
        #pragma unroll
        for (int n = 0; n < 8; n++) {
            bf16x8 b0 = *(const bf16x8*)(Vb + swz(16 * n + l15, 16 * lg));
            bf16x8 b1 = *(const bf16x8*)(Vb + swz(16 * n + l15, 64 + 16 * lg));
            oacc[n] = mfma16(ap0, b0, oacc[n]);
            oacc[n] = mfma16(ap1, b1, oacc[n]);
        }
    }

    // epilogue: per-row LN over 128, * silu(gate), store z
    #pragma unroll
    for (int r = 0; r < 4; r++) {
        float s1 = 0.f, s2 = 0.f;
        #pragma unroll
        for (int n = 0; n < 8; n++) { float v = oacc[n][r]; s1 += v; s2 += v * v; }
        #pragma unroll
        for (int off = 1; off < 16; off <<= 1) { s1 += __shfl_xor(s1, off); s2 += __shfl_xor(s2, off); }
        float mean = s1 * (1.f / 128.f);
        float var = s2 * (1.f / 128.f) - mean * mean;
        float rstd = rsqrtf(var + 1e-5f);
        int il = 16 * wave + 4 * lg + r;
        int s = i0 + il;
        int zrow = b * SEQ + s;
        #pragma unroll
        for (int n = 0; n < 8; n++) {
            int col = 16 * n + l15;
            float y = (oacc[n][r] - mean) * rstd * lng[col] + lnb[col];
            float g = bf2f(gb[zrow * DV + h * VHD + col]);
            zb[zrow * DV + h * VHD + col] = f2bf(y * g);
        }
    }
}

// ---------------- GEMM2: z[4096x2048] @ WoT[1024x2048]^T + bo -> out f32
__global__ __launch_bounds__(256) void gemm2_kernel(
    const unsigned short* __restrict__ Z, const unsigned short* __restrict__ WoT,
    const float* __restrict__ bo, float* __restrict__ out) {
    __shared__ unsigned short As[128 * 32];
    __shared__ unsigned short Bs[128 * 32];
    const int tid = threadIdx.x;
    const int lane = tid & 63, wave = tid >> 6;
    const int wr = wave >> 1, wc = wave & 1;
    const int m0 = blockIdx.y * 128, n0 = blockIdx.x * 128;
    const int l15 = lane & 15, lg = lane >> 4;

    f32x4 acc[4][4];
    #pragma unroll
    for (int i = 0; i < 4; i++)
        #pragma unroll
        for (int j = 0; j < 4; j++) acc[i][j] = (f32x4){0.f, 0.f, 0.f, 0.f};

    const int rowA = tid >> 2, kA = (tid & 3) * 8;

    for (int k0 = 0; k0 < 2048; k0 += 32) {
        __syncthreads();
        gload16(Z + (m0 + rowA) * 2048 + k0 + kA, As + (wave << 9));
        gload16(Z + (m0 + rowA + 64) * 2048 + k0 + kA, As + 2048 + (wave << 9));
        gload16(WoT + (n0 + rowA) * 2048 + k0 + kA, Bs + (wave << 9));
        gload16(WoT + (n0 + rowA + 64) * 2048 + k0 + kA, Bs + 2048 + (wave << 9));
        __syncthreads();
        bf16x8 af[4], bfr[4];
        #pragma unroll
        for (int m = 0; m < 4; m++) af[m] = *(const bf16x8*)&As[(64 * wr + 16 * m + l15) * 32 + 8 * lg];
        #pragma unroll
        for (int n = 0; n < 4; n++) bfr[n] = *(const bf16x8*)&Bs[(64 * wc + 16 * n + l15) * 32 + 8 * lg];
        #pragma unroll
        for (int m = 0; m < 4; m++)
            #pragma unroll
            for (int n = 0; n < 4; n++) acc[m][n] = mfma16(af[m], bfr[n], acc[m][n]);
    }

    #pragma unroll
    for (int n = 0; n < 4; n++) {
        int col = n0 + 64 * wc + 16 * n + l15;
        float bias = bo[col];
        #pragma unroll
        for (int m = 0; m < 4; m++) {
            #pragma unroll
            for (int r = 0; r < 4; r++) {
                int row = m0 + 64 * wr + 16 * m + 4 * lg + r;
                out[row * 1024 + col] = acc[m][n][r] + bias;
            }
        }
    }
}

extern "C" void kernel_launch(void* const* d_in, const int* in_sizes, int n_in,
                              void* d_out, int out_size, void* d_ws, size_t ws_size,
                              hipStream_t stream) {
    (void)in_sizes; (void)n_in; (void)out_size; (void)ws_size;
    const float* x   = (const float*)d_in[0];
    const float* Wq  = (const float*)d_in[2];
    const float* bq  = (const float*)d_in[3];
    const float* Wk  = (const float*)d_in[4];
    const float* bk  = (const float*)d_in[5];
    const float* Wv  = (const float*)d_in[6];
    const float* bv  = (const float*)d_in[7];
    const float* Wg  = (const float*)d_in[8];
    const float* bg  = (const float*)d_in[9];
    const float* Wo  = (const float*)d_in[10];
    const float* bo  = (const float*)d_in[11];
    const float* lpg = (const float*)d_in[12];
    const float* lpb = (const float*)d_in[13];
    const float* lhg = (const float*)d_in[14];
    const float* lhb = (const float*)d_in[15];

    char* w = (char*)d_ws;
    auto alloc = [&](size_t bytes) { char* p = w; w += (bytes + 255) & ~(size_t)255; return p; };
    unsigned short* WT   = (unsigned short*)alloc((size_t)N1 * DIM * 2);
    unsigned short* WoT  = (unsigned short*)alloc((size_t)DIM * DV * 2);
    float*          ball = (float*)alloc((size_t)N1 * 4);
    float*          rsin = (float*)alloc((size_t)SEQ * 64 * 4);
    float*          rcos = (float*)alloc((size_t)SEQ * 64 * 4);
    unsigned short* xn   = (unsigned short*)alloc((size_t)MROWS * DIM * 2);
    unsigned short* qb   = (unsigned short*)alloc((size_t)BATCH * NH * SEQ * KHD * 2);
    unsigned short* kb   = (unsigned short*)alloc((size_t)BATCH * NH * SEQ * KHD * 2);
    unsigned short* vb   = (unsigned short*)alloc((size_t)BATCH * NH * VHD * SEQ * 2);
    unsigned short* gb   = (unsigned short*)alloc((size_t)MROWS * DV * 2);
    unsigned short* zb   = (unsigned short*)alloc((size_t)MROWS * DV * 2);

    dim3 tb(32, 8);
    transpose_cvt<<<dim3(32, 32), tb, 0, stream>>>(Wq, WT + 0 * DIM, DIM, DIM);
    transpose_cvt<<<dim3(32, 32), tb, 0, stream>>>(Wk, WT + 1024 * DIM, DIM, DIM);
    transpose_cvt<<<dim3(64, 32), tb, 0, stream>>>(Wv, WT + 2048 * DIM, DIM, DV);
    transpose_cvt<<<dim3(64, 32), tb, 0, stream>>>(Wg, WT + 4096 * DIM, DIM, DV);
    transpose_cvt<<<dim3(32, 64), tb, 0, stream>>>(Wo, WoT, DV, DIM);
    bias_concat<<<24, 256, 0, stream>>>(bq, bk, bv, bg, ball);
    rope_kernel<<<256, 256, 0, stream>>>(rsin, rcos);
    ln_x_kernel<<<MROWS, 256, 0, stream>>>(x, lpg, lpb, xn);
    gemm1_kernel<<<dim3(48, 32), 256, 0, stream>>>(xn, WT, ball, rsin, rcos, qb, kb, vb, gb);
    retention_kernel<<<dim3(32, 32), 256, 0, stream>>>(qb, kb, vb, gb, lhg, lhb, zb);
    gemm2_kernel<<<dim3(8, 32), 256, 0, stream>>>(zb, WoT, bo, (float*)d_out);
}

// Round 9
// 333.356 us; speedup vs baseline: 1.5450x; 1.4012x over previous
//
#include <hip/hip_runtime.h>
#include <hip/hip_bf16.h>
#include <math.h>

#define DEVINL __device__ __forceinline__

typedef __attribute__((ext_vector_type(4))) float f32x4;
typedef __attribute__((ext_vector_type(8))) short bf16x8;

constexpr int BATCH = 2;
constexpr int SEQ   = 2048;
constexpr int DIM   = 1024;
constexpr int NH    = 16;
constexpr int KHD   = 64;    // key head dim
constexpr int VHD   = 128;   // value head dim
constexpr int DV    = 2048;  // D * VF
constexpr int MROWS = BATCH * SEQ;      // 4096
constexpr int N1    = DIM + DIM + DV + DV; // 6144
constexpr int NCHUNK = SEQ / 64;        // 32

DEVINL unsigned short f2bf(float f) {
    union { float f; unsigned int u; } c; c.f = f;
    unsigned int u = c.u;
    u += 0x7FFFu + ((u >> 16) & 1u);
    return (unsigned short)(u >> 16);
}
DEVINL float bf2f(unsigned short h) {
    union { unsigned int u; float f; } c; c.u = ((unsigned int)h) << 16;
    return c.f;
}
DEVINL f32x4 mfma16(bf16x8 a, bf16x8 b, f32x4 c) {
    return __builtin_amdgcn_mfma_f32_16x16x32_bf16(a, b, c, 0, 0, 0);
}
// async global->LDS, 16B per lane; l must be the wave-uniform base (lane*16B implicit)
DEVINL void gload16(const unsigned short* g, unsigned short* l) {
    __builtin_amdgcn_global_load_lds(
        (const __attribute__((address_space(1))) unsigned int*)g,
        (__attribute__((address_space(3))) unsigned int*)l, 16, 0, 0);
}
// XOR swizzle for 128B-row LDS tiles: 16B chunk slot = chunkidx ^ (row&7)
DEVINL int swz(int row, int colb) { return row * 128 + (colb ^ ((row & 7) << 4)); }

// ---------------- weight transpose + bf16 convert: src KxN f32 -> dst NxK bf16
__global__ __launch_bounds__(256) void transpose_cvt(const float* __restrict__ src,
                                                     unsigned short* __restrict__ dst,
                                                     int K, int N) {
    __shared__ float t[32][33];
    int bx = blockIdx.x * 32;  // N dim
    int by = blockIdx.y * 32;  // K dim
    int x = threadIdx.x, y = threadIdx.y;  // (32, 8)
    #pragma unroll
    for (int i = 0; i < 32; i += 8) t[y + i][x] = src[(by + y + i) * N + bx + x];
    __syncthreads();
    #pragma unroll
    for (int i = 0; i < 32; i += 8) dst[(bx + y + i) * K + by + x] = f2bf(t[x][y + i]);
}

__global__ void bias_concat(const float* __restrict__ bq, const float* __restrict__ bk,
                            const float* __restrict__ bv, const float* __restrict__ bg,
                            float* __restrict__ ball) {
    int t = blockIdx.x * 256 + threadIdx.x;
    float v;
    if (t < 1024) v = bq[t];
    else if (t < 2048) v = bk[t - 1024];
    else if (t < 4096) v = bv[t - 2048];
    else v = bg[t - 4096];
    ball[t] = v;
}

__global__ void rope_kernel(float* __restrict__ rsin, float* __restrict__ rcos) {
    int t = blockIdx.x * 256 + threadIdx.x;  // 0..65535
    int s = t >> 5, i = t & 31;
    float ang = powf(10000.f, -(float)i / 31.f);
    float th = (float)s * ang;
    float sv, cv;
    sincosf(th, &sv, &cv);
    rsin[s * 64 + 2 * i] = sv; rsin[s * 64 + 2 * i + 1] = sv;
    rcos[s * 64 + 2 * i] = cv; rcos[s * 64 + 2 * i + 1] = cv;
}

// ---------------- LayerNorm of x -> bf16
__global__ __launch_bounds__(256) void ln_x_kernel(const float* __restrict__ x,
                                                   const float* __restrict__ g,
                                                   const float* __restrict__ b,
                                                   unsigned short* __restrict__ xn) {
    int row = blockIdx.x;
    int t = threadIdx.x;
    const float4 v = *(const float4*)(x + row * 1024 + t * 4);
    float s1 = v.x + v.y + v.z + v.w;
    float s2 = v.x * v.x + v.y * v.y + v.z * v.z + v.w * v.w;
    #pragma unroll
    for (int off = 1; off < 64; off <<= 1) { s1 += __shfl_xor(s1, off); s2 += __shfl_xor(s2, off); }
    __shared__ float red[8];
    int wave = t >> 6, lane = t & 63;
    if (lane == 0) { red[wave] = s1; red[4 + wave] = s2; }
    __syncthreads();
    s1 = red[0] + red[1] + red[2] + red[3];
    s2 = red[4] + red[5] + red[6] + red[7];
    float mean = s1 * (1.f / 1024.f);
    float rstd = rsqrtf(s2 * (1.f / 1024.f) - mean * mean + 1e-5f);
    const float4 gv = *(const float4*)(g + t * 4);
    const float4 bv = *(const float4*)(b + t * 4);
    ushort4 o;
    o.x = f2bf((v.x - mean) * rstd * gv.x + bv.x);
    o.y = f2bf((v.y - mean) * rstd * gv.y + bv.y);
    o.z = f2bf((v.z - mean) * rstd * gv.z + bv.z);
    o.w = f2bf((v.w - mean) * rstd * gv.w + bv.w);
    *(ushort4*)&xn[row * 1024 + t * 4] = o;
}

// ---------------- GEMM1: xn[4096x1024] @ WT[6144x1024]^T + epilogue
// epilogue: bias, k-scale, RoPE (q,k), silu (gate); writes q(s,kd), k(s,kd),
// kT(kd,s), v^T(vd,s), gate.
__global__ __launch_bounds__(256) void gemm1_kernel(
    const unsigned short* __restrict__ Abf, const unsigned short* __restrict__ WT,
    const float* __restrict__ ball, const float* __restrict__ rsin,
    const float* __restrict__ rcos, unsigned short* __restrict__ qb,
    unsigned short* __restrict__ kb, unsigned short* __restrict__ kbT,
    unsigned short* __restrict__ vb, unsigned short* __restrict__ gb) {
    __shared__ unsigned short As[128 * 32];
    __shared__ unsigned short Bs[128 * 32];
    const int tid = threadIdx.x;
    const int lane = tid & 63, wave = tid >> 6;
    const int wr = wave >> 1, wc = wave & 1;
    const int m0 = blockIdx.y * 128, n0 = blockIdx.x * 128;
    const int l15 = lane & 15, lg = lane >> 4;

    f32x4 acc[4][4];
    #pragma unroll
    for (int i = 0; i < 4; i++)
        #pragma unroll
        for (int j = 0; j < 4; j++) acc[i][j] = (f32x4){0.f, 0.f, 0.f, 0.f};

    const int rowA = tid >> 2, kA = (tid & 3) * 8;   // lane-linear: LDS byte = tid*16

    for (int k0 = 0; k0 < 1024; k0 += 32) {
        __syncthreads();
        gload16(Abf + (m0 + rowA) * 1024 + k0 + kA, As + (wave << 9));
        gload16(Abf + (m0 + rowA + 64) * 1024 + k0 + kA, As + 2048 + (wave << 9));
        gload16(WT + (n0 + rowA) * 1024 + k0 + kA, Bs + (wave << 9));
        gload16(WT + (n0 + rowA + 64) * 1024 + k0 + kA, Bs + 2048 + (wave << 9));
        __syncthreads();
        bf16x8 af[4], bfr[4];
        #pragma unroll
        for (int m = 0; m < 4; m++) af[m] = *(const bf16x8*)&As[(64 * wr + 16 * m + l15) * 32 + 8 * lg];
        #pragma unroll
        for (int n = 0; n < 4; n++) bfr[n] = *(const bf16x8*)&Bs[(64 * wc + 16 * n + l15) * 32 + 8 * lg];
        #pragma unroll
        for (int m = 0; m < 4; m++)
            #pragma unroll
            for (int n = 0; n < 4; n++) acc[m][n] = mfma16(af[m], bfr[n], acc[m][n]);
    }

    const int rowbase = m0 + 64 * wr + 4 * lg;  // + 16*m + r
    const int colbase = n0 + 64 * wc + l15;     // + 16*n
    #pragma unroll
    for (int n = 0; n < 4; n++) {
        int col = colbase + 16 * n;
        float bias = ball[col];
        if (col < 2048) {                       // q or k with RoPE
            bool isK = col >= 1024;
            int c = col & 1023;
            int hh = c >> 6, d = c & 63;
            unsigned short* dst = isK ? kb : qb;
            #pragma unroll
            for (int m = 0; m < 4; m++) {
                float resv[4];
                #pragma unroll
                for (int r = 0; r < 4; r++) {
                    int row = rowbase + 16 * m + r;
                    int s = row & (SEQ - 1);
                    int bsel = row >> 11;
                    float v = acc[m][n][r] + bias;
                    if (isK) v *= 0.125f;
                    float cs = rcos[s * 64 + d], sn = rsin[s * 64 + d];
                    float pv = __shfl_xor(v, 1);
                    float res = ((d & 1) == 0) ? (v * cs - pv * sn) : (v * cs + pv * sn);
                    resv[r] = res;
                    float pr = __shfl_xor(res, 1);
                    if ((lane & 1) == 0) {
                        unsigned int pk = (unsigned int)f2bf(res) | ((unsigned int)f2bf(pr) << 16);
                        *(unsigned int*)&dst[(((bsel * NH + hh) * SEQ) + s) * KHD + d] = pk;
                    }
                }
                if (isK) {                       // transposed K copy (b,h,kd,s)
                    int row0 = rowbase + 16 * m;
                    int s0 = row0 & (SEQ - 1);
                    int bsel = row0 >> 11;
                    ushort4 u4;
                    u4.x = f2bf(resv[0]); u4.y = f2bf(resv[1]);
                    u4.z = f2bf(resv[2]); u4.w = f2bf(resv[3]);
                    *(ushort4*)&kbT[(((bsel * NH + hh) * KHD) + d) * SEQ + s0] = u4;
                }
            }
        } else if (col < 4096) {                // v -> transposed (b,h,vd,s)
            int c = col - 2048;
            int hh = c >> 7, vd = c & 127;
            #pragma unroll
            for (int m = 0; m < 4; m++) {
                int row = rowbase + 16 * m;
                int s = row & (SEQ - 1);
                int bsel = row >> 11;
                ushort4 u4;
                u4.x = f2bf(acc[m][n][0] + bias);
                u4.y = f2bf(acc[m][n][1] + bias);
                u4.z = f2bf(acc[m][n][2] + bias);
                u4.w = f2bf(acc[m][n][3] + bias);
                *(ushort4*)&vb[(((bsel * NH + hh) * VHD) + vd) * SEQ + s] = u4;
            }
        } else {                                // gate -> silu, (b,s,2048)
            int c = col - 4096;
            #pragma unroll
            for (int m = 0; m < 4; m++) {
                #pragma unroll
                for (int r = 0; r < 4; r++) {
                    int row = rowbase + 16 * m + r;
                    int s = row & (SEQ - 1);
                    int bsel = row >> 11;
                    float v = acc[m][n][r] + bias;
                    float sg = v / (1.f + expf(-v));
                    float pr = __shfl_xor(sg, 1);
                    if ((lane & 1) == 0) {
                        unsigned int pk = (unsigned int)f2bf(sg) | ((unsigned int)f2bf(pr) << 16);
                        *(unsigned int*)&gb[((bsel * SEQ + s) * DV) + c] = pk;
                    }
                }
            }
        }
    }
}

// ---------------- pass 1: per-chunk decay-weighted KV state
// A_c[vd,kd] = sum_{j in chunk} lambda^{64-j~} k[j,kd] v[j,vd]   (f32)
__global__ __launch_bounds__(256) void chunk_kv_kernel(
    const unsigned short* __restrict__ kbT, const unsigned short* __restrict__ vb,
    float* __restrict__ Araw) {
    __shared__ char KT[64 * 128];    // kd x s(64)
    __shared__ char VT[128 * 128];   // vd x s(64)
    const int tid = threadIdx.x, lane = tid & 63, wave = tid >> 6;
    const int l15 = lane & 15, lg = lane >> 4;
    const int c = blockIdx.x, bh = blockIdx.y;
    const int h = bh & 15;
    const float dl2 = log1pf(-exp2f(-(float)(5 + h))) * 1.44269504088896f;

    // stage K^T with decay scale lambda^{64 - s~}
    #pragma unroll
    for (int it = 0; it < 2; ++it) {
        int idx = tid + it * 256;            // 0..511
        int kd = idx >> 3, sc = (idx & 7) * 8;
        uint4 raw = *(const uint4*)(kbT + ((size_t)(bh * KHD + kd)) * SEQ + c * 64 + sc);
        unsigned short* rs = (unsigned short*)&raw;
        unsigned short outv[8];
        #pragma unroll
        for (int e = 0; e < 8; ++e)
            outv[e] = f2bf(bf2f(rs[e]) * exp2f((float)(64 - (sc + e)) * dl2));
        *(uint4*)(KT + swz(kd, sc * 2)) = *(uint4*)outv;
    }
    // stage V^T
    #pragma unroll
    for (int it = 0; it < 4; ++it) {
        int idx = tid + it * 256;            // 0..1023
        int vd = idx >> 3, sc = (idx & 7) * 8;
        uint4 raw = *(const uint4*)(vb + ((size_t)(bh * VHD + vd)) * SEQ + c * 64 + sc);
        *(uint4*)(VT + swz(vd, sc * 2)) = raw;
    }
    __syncthreads();

    f32x4 acc[2][4];
    #pragma unroll
    for (int m = 0; m < 2; m++)
        #pragma unroll
        for (int n = 0; n < 4; n++) acc[m][n] = (f32x4){0.f, 0.f, 0.f, 0.f};

    #pragma unroll
    for (int k = 0; k < 2; k++) {
        int colb = 64 * k + 16 * lg;
        bf16x8 af[2], bfr[4];
        #pragma unroll
        for (int m = 0; m < 2; m++) af[m] = *(const bf16x8*)(VT + swz(32 * wave + 16 * m + l15, colb));
        #pragma unroll
        for (int n = 0; n < 4; n++) bfr[n] = *(const bf16x8*)(KT + swz(16 * n + l15, colb));
        #pragma unroll
        for (int m = 0; m < 2; m++)
            #pragma unroll
            for (int n = 0; n < 4; n++) acc[m][n] = mfma16(af[m], bfr[n], acc[m][n]);
    }

    float* base = Araw + ((size_t)(bh * NCHUNK + c)) * (VHD * KHD);
    #pragma unroll
    for (int m = 0; m < 2; m++)
        #pragma unroll
        for (int n = 0; n < 4; n++) {
            int col = 16 * n + l15;
            #pragma unroll
            for (int r = 0; r < 4; r++) {
                int row = 32 * wave + 16 * m + 4 * lg + r;
                base[row * KHD + col] = acc[m][n][r];
            }
        }
}

// ---------------- pass 2: scan  S_{t+1} = lambda^64 * S_t + A_t ; state[t] = S_t (bf16)
__global__ __launch_bounds__(256) void scan_kernel(
    const float* __restrict__ Araw, unsigned short* __restrict__ state) {
    const int slice = blockIdx.x, bh = blockIdx.y;
    const int h = bh & 15;
    const float dl2 = log1pf(-exp2f(-(float)(5 + h))) * 1.44269504088896f;
    const float l64 = exp2f(64.f * dl2);
    const int elem = slice * 1024 + threadIdx.x * 4;

    float4 S = {0.f, 0.f, 0.f, 0.f};
    float4 a = *(const float4*)&Araw[((size_t)(bh * NCHUNK)) * 8192 + elem];
    #pragma unroll 4
    for (int t = 0; t < NCHUNK; ++t) {
        float4 an;
        if (t < NCHUNK - 1)
            an = *(const float4*)&Araw[((size_t)(bh * NCHUNK + t + 1)) * 8192 + elem];
        ushort4 o;
        o.x = f2bf(S.x); o.y = f2bf(S.y); o.z = f2bf(S.z); o.w = f2bf(S.w);
        *(ushort4*)&state[((size_t)(bh * NCHUNK + t)) * 8192 + elem] = o;
        S.x = l64 * S.x + a.x; S.y = l64 * S.y + a.y;
        S.z = l64 * S.z + a.z; S.w = l64 * S.w + a.w;
        a = an;
    }
}

// ---------------- pass 3: O[i] = intra(diag tile) + lambda^{i~} * q_i . S_t
// then per-row LN over VD, * silu(gate), write z
__global__ __launch_bounds__(256) void retention2_kernel(
    const unsigned short* __restrict__ qb, const unsigned short* __restrict__ kb,
    const unsigned short* __restrict__ vb, const unsigned short* __restrict__ state,
    const unsigned short* __restrict__ gb, const float* __restrict__ lng,
    const float* __restrict__ lnb, unsigned short* __restrict__ zb) {
    __shared__ char Kb[64 * 128];
    __shared__ char Pb[64 * 128];
    __shared__ char Vb[128 * 128];
    __shared__ char Sb[128 * 128];
    const int tid = threadIdx.x, lane = tid & 63, wave = tid >> 6;
    const int l15 = lane & 15, lg = lane >> 4;
    const int itile = blockIdx.x, bh = blockIdx.y;
    const int b = bh >> 4, h = bh & 15;
    const int i0 = itile * 64;
    const float dl2 = log1pf(-exp2f(-(float)(5 + h))) * 1.44269504088896f;

    const int srow = tid >> 3, scolb = (tid & 7) * 16;

    {   // stage K (s,kd)
        const unsigned short* kbase = kb + (bh * SEQ + i0) * KHD;
        uint4 k0 = *(const uint4*)(kbase + tid * 8);
        uint4 k1 = *(const uint4*)(kbase + tid * 8 + 2048);
        *(uint4*)(Kb + swz(srow, scolb)) = k0;
        *(uint4*)(Kb + swz(srow + 32, scolb)) = k1;
        // stage V^T (vd, s)
        const unsigned short* vbase = vb + (size_t)bh * VHD * SEQ;
        #pragma unroll
        for (int it = 0; it < 4; ++it) {
            int o = tid * 8 + it * 2048;
            uint4 vv = *(const uint4*)(vbase + (o >> 6) * SEQ + i0 + (o & 63));
            *(uint4*)(Vb + swz(o >> 6, (o & 63) * 2)) = vv;
        }
        // stage S_t (vd, kd) bf16
        const unsigned short* sbase = state + ((size_t)(bh * NCHUNK + itile)) * 8192;
        #pragma unroll
        for (int it = 0; it < 4; ++it) {
            int o = tid * 8 + it * 2048;
            uint4 sv = *(const uint4*)(sbase + o);
            *(uint4*)(Sb + swz(o >> 6, (o & 63) * 2)) = sv;
        }
    }
    // Q fragments straight from global (L2-resident, each used many times in-reg)
    const unsigned short* qrow = qb + (bh * SEQ + i0 + 16 * wave + l15) * KHD;
    bf16x8 aq0 = *(const bf16x8*)(qrow + 8 * lg);
    bf16x8 aq1 = *(const bf16x8*)(qrow + 32 + 8 * lg);
    __syncthreads();

    // diagonal decay factors lambda^{il-jl} masked
    float based[4][4];
    #pragma unroll
    for (int n = 0; n < 4; n++)
        #pragma unroll
        for (int r = 0; r < 4; r++) {
            int d = (4 * lg + r) - (16 * n + l15) + 16 * wave;
            based[n][r] = (d >= 0) ? exp2f((float)d * dl2) : 0.f;
        }

    // intra: QK^T on diagonal tile
    f32x4 pacc[4];
    #pragma unroll
    for (int n = 0; n < 4; n++) pacc[n] = (f32x4){0.f, 0.f, 0.f, 0.f};
    #pragma unroll
    for (int n = 0; n < 4; n++) {
        bf16x8 b0 = *(const bf16x8*)(Kb + swz(16 * n + l15, 16 * lg));
        bf16x8 b1 = *(const bf16x8*)(Kb + swz(16 * n + l15, 64 + 16 * lg));
        pacc[n] = mfma16(aq0, b0, pacc[n]);
        pacc[n] = mfma16(aq1, b1, pacc[n]);
    }
    #pragma unroll
    for (int n = 0; n < 4; n++)
        #pragma unroll
        for (int r = 0; r < 4; r++) {
            int il = 16 * wave + 4 * lg + r;
            int jl = 16 * n + l15;
            *(unsigned short*)(Pb + swz(il, jl * 2)) = f2bf(pacc[n][r] * based[n][r]);
        }
    bf16x8 ap0 = *(const bf16x8*)(Pb + swz(16 * wave + l15, 16 * lg));
    bf16x8 ap1 = *(const bf16x8*)(Pb + swz(16 * wave + l15, 64 + 16 * lg));

    f32x4 oacc[8], cacc[8];
    #pragma unroll
    for (int n = 0; n < 8; n++) {
        oacc[n] = (f32x4){0.f, 0.f, 0.f, 0.f};
        cacc[n] = (f32x4){0.f, 0.f, 0.f, 0.f};
    }
    #pragma unroll
    for (int n = 0; n < 8; n++) {
        bf16x8 b0 = *(const bf16x8*)(Vb + swz(16 * n + l15, 16 * lg));
        bf16x8 b1 = *(const bf16x8*)(Vb + swz(16 * n + l15, 64 + 16 * lg));
        oacc[n] = mfma16(ap0, b0, oacc[n]);
        oacc[n] = mfma16(ap1, b1, oacc[n]);
        bf16x8 s0 = *(const bf16x8*)(Sb + swz(16 * n + l15, 16 * lg));
        bf16x8 s1 = *(const bf16x8*)(Sb + swz(16 * n + l15, 64 + 16 * lg));
        cacc[n] = mfma16(aq0, s0, cacc[n]);
        cacc[n] = mfma16(aq1, s1, cacc[n]);
    }

    // combine, LN over 128, silu(gate), store
    #pragma unroll
    for (int r = 0; r < 4; r++) {
        int il = 16 * wave + 4 * lg + r;
        float lamI = exp2f((float)il * dl2);
        float ov[8];
        float s1 = 0.f, s2 = 0.f;
        #pragma unroll
        for (int n = 0; n < 8; n++) {
            float v = oacc[n][r] + lamI * cacc[n][r];
            ov[n] = v; s1 += v; s2 += v * v;
        }
        #pragma unroll
        for (int off = 1; off < 16; off <<= 1) { s1 += __shfl_xor(s1, off); s2 += __shfl_xor(s2, off); }
        float mean = s1 * (1.f / 128.f);
        float var = s2 * (1.f / 128.f) - mean * mean;
        float rstd = rsqrtf(var + 1e-5f);
        int s = i0 + il;
        int zrow = b * SEQ + s;
        #pragma unroll
        for (int n = 0; n < 8; n++) {
            int col = 16 * n + l15;
            float y = (ov[n] - mean) * rstd * lng[col] + lnb[col];
            float g = bf2f(gb[zrow * DV + h * VHD + col]);
            zb[zrow * DV + h * VHD + col] = f2bf(y * g);
        }
    }
}

// ---------------- GEMM2: z[4096x2048] @ WoT[1024x2048]^T + bo -> out f32
__global__ __launch_bounds__(256) void gemm2_kernel(
    const unsigned short* __restrict__ Z, const unsigned short* __restrict__ WoT,
    const float* __restrict__ bo, float* __restrict__ out) {
    __shared__ unsigned short As[128 * 32];
    __shared__ unsigned short Bs[128 * 32];
    const int tid = threadIdx.x;
    const int lane = tid & 63, wave = tid >> 6;
    const int wr = wave >> 1, wc = wave & 1;
    const int m0 = blockIdx.y * 128, n0 = blockIdx.x * 128;
    const int l15 = lane & 15, lg = lane >> 4;

    f32x4 acc[4][4];
    #pragma unroll
    for (int i = 0; i < 4; i++)
        #pragma unroll
        for (int j = 0; j < 4; j++) acc[i][j] = (f32x4){0.f, 0.f, 0.f, 0.f};

    const int rowA = tid >> 2, kA = (tid & 3) * 8;

    for (int k0 = 0; k0 < 2048; k0 += 32) {
        __syncthreads();
        gload16(Z + (m0 + rowA) * 2048 + k0 + kA, As + (wave << 9));
        gload16(Z + (m0 + rowA + 64) * 2048 + k0 + kA, As + 2048 + (wave << 9));
        gload16(WoT + (n0 + rowA) * 2048 + k0 + kA, Bs + (wave << 9));
        gload16(WoT + (n0 + rowA + 64) * 2048 + k0 + kA, Bs + 2048 + (wave << 9));
        __syncthreads();
        bf16x8 af[4], bfr[4];
        #pragma unroll
        for (int m = 0; m < 4; m++) af[m] = *(const bf16x8*)&As[(64 * wr + 16 * m + l15) * 32 + 8 * lg];
        #pragma unroll
        for (int n = 0; n < 4; n++) bfr[n] = *(const bf16x8*)&Bs[(64 * wc + 16 * n + l15) * 32 + 8 * lg];
        #pragma unroll
        for (int m = 0; m < 4; m++)
            #pragma unroll
            for (int n = 0; n < 4; n++) acc[m][n] = mfma16(af[m], bfr[n], acc[m][n]);
    }

    #pragma unroll
    for (int n = 0; n < 4; n++) {
        int col = n0 + 64 * wc + 16 * n + l15;
        float bias = bo[col];
        #pragma unroll
        for (int m = 0; m < 4; m++) {
            #pragma unroll
            for (int r = 0; r < 4; r++) {
                int row = m0 + 64 * wr + 16 * m + 4 * lg + r;
                out[row * 1024 + col] = acc[m][n][r] + bias;
            }
        }
    }
}

extern "C" void kernel_launch(void* const* d_in, const int* in_sizes, int n_in,
                              void* d_out, int out_size, void* d_ws, size_t ws_size,
                              hipStream_t stream) {
    (void)in_sizes; (void)n_in; (void)out_size; (void)ws_size;
    const float* x   = (const float*)d_in[0];
    const float* Wq  = (const float*)d_in[2];
    const float* bq  = (const float*)d_in[3];
    const float* Wk  = (const float*)d_in[4];
    const float* bk  = (const float*)d_in[5];
    const float* Wv  = (const float*)d_in[6];
    const float* bv  = (const float*)d_in[7];
    const float* Wg  = (const float*)d_in[8];
    const float* bg  = (const float*)d_in[9];
    const float* Wo  = (const float*)d_in[10];
    const float* bo  = (const float*)d_in[11];
    const float* lpg = (const float*)d_in[12];
    const float* lpb = (const float*)d_in[13];
    const float* lhg = (const float*)d_in[14];
    const float* lhb = (const float*)d_in[15];

    char* w = (char*)d_ws;
    auto alloc = [&](size_t bytes) { char* p = w; w += (bytes + 255) & ~(size_t)255; return p; };
    unsigned short* WT    = (unsigned short*)alloc((size_t)N1 * DIM * 2);
    unsigned short* WoT   = (unsigned short*)alloc((size_t)DIM * DV * 2);
    float*          ball  = (float*)alloc((size_t)N1 * 4);
    float*          rsin  = (float*)alloc((size_t)SEQ * 64 * 4);
    float*          rcos  = (float*)alloc((size_t)SEQ * 64 * 4);
    unsigned short* xn    = (unsigned short*)alloc((size_t)MROWS * DIM * 2);
    unsigned short* qb    = (unsigned short*)alloc((size_t)BATCH * NH * SEQ * KHD * 2);
    unsigned short* kb    = (unsigned short*)alloc((size_t)BATCH * NH * SEQ * KHD * 2);
    unsigned short* kbT   = (unsigned short*)alloc((size_t)BATCH * NH * KHD * SEQ * 2);
    unsigned short* vb    = (unsigned short*)alloc((size_t)BATCH * NH * VHD * SEQ * 2);
    unsigned short* gb    = (unsigned short*)alloc((size_t)MROWS * DV * 2);
    unsigned short* zb    = (unsigned short*)alloc((size_t)MROWS * DV * 2);
    float*          Araw  = (float*)alloc((size_t)BATCH * NH * NCHUNK * VHD * KHD * 4);
    unsigned short* stateb= (unsigned short*)alloc((size_t)BATCH * NH * NCHUNK * VHD * KHD * 2);

    dim3 tb(32, 8);
    transpose_cvt<<<dim3(32, 32), tb, 0, stream>>>(Wq, WT + 0 * DIM, DIM, DIM);
    transpose_cvt<<<dim3(32, 32), tb, 0, stream>>>(Wk, WT + 1024 * DIM, DIM, DIM);
    transpose_cvt<<<dim3(64, 32), tb, 0, stream>>>(Wv, WT + 2048 * DIM, DIM, DV);
    transpose_cvt<<<dim3(64, 32), tb, 0, stream>>>(Wg, WT + 4096 * DIM, DIM, DV);
    transpose_cvt<<<dim3(32, 64), tb, 0, stream>>>(Wo, WoT, DV, DIM);
    bias_concat<<<24, 256, 0, stream>>>(bq, bk, bv, bg, ball);
    rope_kernel<<<256, 256, 0, stream>>>(rsin, rcos);
    ln_x_kernel<<<MROWS, 256, 0, stream>>>(x, lpg, lpb, xn);
    gemm1_kernel<<<dim3(48, 32), 256, 0, stream>>>(xn, WT, ball, rsin, rcos, qb, kb, kbT, vb, gb);
    chunk_kv_kernel<<<dim3(NCHUNK, 32), 256, 0, stream>>>(kbT, vb, Araw);
    scan_kernel<<<dim3(8, 32), 256, 0, stream>>>(Araw, stateb);
    retention2_kernel<<<dim3(NCHUNK, 32), 256, 0, stream>>>(qb, kb, vb, stateb, gb, lhg, lhb, zb);
    gemm2_kernel<<<dim3(8, 32), 256, 0, stream>>>(zb, WoT, bo, (float*)d_out);
}

// Round 10
// 329.559 us; speedup vs baseline: 1.5628x; 1.0115x over previous
//
#include <hip/hip_runtime.h>
#include <hip/hip_bf16.h>
#include <math.h>

#define DEVINL __device__ __forceinline__

typedef __attribute__((ext_vector_type(4))) float f32x4;
typedef __attribute__((ext_vector_type(8))) short bf16x8;

constexpr int BATCH = 2;
constexpr int SEQ   = 2048;
constexpr int DIM   = 1024;
constexpr int NH    = 16;
constexpr int KHD   = 64;    // key head dim
constexpr int VHD   = 128;   // value head dim
constexpr int DV    = 2048;  // D * VF
constexpr int MROWS = BATCH * SEQ;      // 4096
constexpr int N1    = DIM + DIM + DV + DV; // 6144
constexpr int NCHUNK = SEQ / 64;        // 32

DEVINL unsigned short f2bf(float f) {
    union { float f; unsigned int u; } c; c.f = f;
    unsigned int u = c.u;
    u += 0x7FFFu + ((u >> 16) & 1u);
    return (unsigned short)(u >> 16);
}
DEVINL float bf2f(unsigned short h) {
    union { unsigned int u; float f; } c; c.u = ((unsigned int)h) << 16;
    return c.f;
}
DEVINL f32x4 mfma16(bf16x8 a, bf16x8 b, f32x4 c) {
    return __builtin_amdgcn_mfma_f32_16x16x32_bf16(a, b, c, 0, 0, 0);
}
// async global->LDS, 16B per lane; l must be the wave-uniform base (lane*16B implicit)
DEVINL void gload16(const unsigned short* g, const unsigned short* l) {
    __builtin_amdgcn_global_load_lds(
        (const __attribute__((address_space(1))) unsigned int*)g,
        (__attribute__((address_space(3))) unsigned int*)(unsigned short*)l, 16, 0, 0);
}
// XOR swizzle for 128B-row LDS tiles: 16B chunk slot = chunkidx ^ (row&7)
DEVINL int swz(int row, int colb) { return row * 128 + (colb ^ ((row & 7) << 4)); }

// ---------------- weight transpose + bf16 convert: src KxN f32 -> dst NxK bf16
__global__ __launch_bounds__(256) void transpose_cvt(const float* __restrict__ src,
                                                     unsigned short* __restrict__ dst,
                                                     int K, int N) {
    __shared__ float t[32][33];
    int bx = blockIdx.x * 32;  // N dim
    int by = blockIdx.y * 32;  // K dim
    int x = threadIdx.x, y = threadIdx.y;  // (32, 8)
    #pragma unroll
    for (int i = 0; i < 32; i += 8) t[y + i][x] = src[(by + y + i) * N + bx + x];
    __syncthreads();
    #pragma unroll
    for (int i = 0; i < 32; i += 8) dst[(bx + y + i) * K + by + x] = f2bf(t[x][y + i]);
}

__global__ void bias_concat(const float* __restrict__ bq, const float* __restrict__ bk,
                            const float* __restrict__ bv, const float* __restrict__ bg,
                            float* __restrict__ ball) {
    int t = blockIdx.x * 256 + threadIdx.x;
    float v;
    if (t < 1024) v = bq[t];
    else if (t < 2048) v = bk[t - 1024];
    else if (t < 4096) v = bv[t - 2048];
    else v = bg[t - 4096];
    ball[t] = v;
}

__global__ void rope_kernel(float* __restrict__ rsin, float* __restrict__ rcos) {
    int t = blockIdx.x * 256 + threadIdx.x;  // 0..65535
    int s = t >> 5, i = t & 31;
    float ang = powf(10000.f, -(float)i / 31.f);
    float th = (float)s * ang;
    float sv, cv;
    sincosf(th, &sv, &cv);
    rsin[s * 64 + 2 * i] = sv; rsin[s * 64 + 2 * i + 1] = sv;
    rcos[s * 64 + 2 * i] = cv; rcos[s * 64 + 2 * i + 1] = cv;
}

// ---------------- LayerNorm of x -> bf16
__global__ __launch_bounds__(256) void ln_x_kernel(const float* __restrict__ x,
                                                   const float* __restrict__ g,
                                                   const float* __restrict__ b,
                                                   unsigned short* __restrict__ xn) {
    int row = blockIdx.x;
    int t = threadIdx.x;
    const float4 v = *(const float4*)(x + row * 1024 + t * 4);
    float s1 = v.x + v.y + v.z + v.w;
    float s2 = v.x * v.x + v.y * v.y + v.z * v.z + v.w * v.w;
    #pragma unroll
    for (int off = 1; off < 64; off <<= 1) { s1 += __shfl_xor(s1, off); s2 += __shfl_xor(s2, off); }
    __shared__ float red[8];
    int wave = t >> 6, lane = t & 63;
    if (lane == 0) { red[wave] = s1; red[4 + wave] = s2; }
    __syncthreads();
    s1 = red[0] + red[1] + red[2] + red[3];
    s2 = red[4] + red[5] + red[6] + red[7];
    float mean = s1 * (1.f / 1024.f);
    float rstd = rsqrtf(s2 * (1.f / 1024.f) - mean * mean + 1e-5f);
    const float4 gv = *(const float4*)(g + t * 4);
    const float4 bv = *(const float4*)(b + t * 4);
    ushort4 o;
    o.x = f2bf((v.x - mean) * rstd * gv.x + bv.x);
    o.y = f2bf((v.y - mean) * rstd * gv.y + bv.y);
    o.z = f2bf((v.z - mean) * rstd * gv.z + bv.z);
    o.w = f2bf((v.w - mean) * rstd * gv.w + bv.w);
    *(ushort4*)&xn[row * 1024 + t * 4] = o;
}

// ---------------- GEMM1: xn[4096x1024] @ WT[6144x1024]^T + epilogue
// K-loop: BK=64, pre-swizzled global_load_lds staging + swizzled b128 reads.
__global__ __launch_bounds__(256) void gemm1_kernel(
    const unsigned short* __restrict__ Abf, const unsigned short* __restrict__ WT,
    const float* __restrict__ ball, const float* __restrict__ rsin,
    const float* __restrict__ rcos, unsigned short* __restrict__ qb,
    unsigned short* __restrict__ kb, unsigned short* __restrict__ kbT,
    unsigned short* __restrict__ vb, unsigned short* __restrict__ gb) {
    __shared__ char As[128 * 128];
    __shared__ char Bs[128 * 128];
    const int tid = threadIdx.x;
    const int lane = tid & 63, wave = tid >> 6;
    const int wr = wave >> 1, wc = wave & 1;
    const int m0 = blockIdx.y * 128, n0 = blockIdx.x * 128;
    const int l15 = lane & 15, lg = lane >> 4;

    f32x4 acc[4][4];
    #pragma unroll
    for (int i = 0; i < 4; i++)
        #pragma unroll
        for (int j = 0; j < 4; j++) acc[i][j] = (f32x4){0.f, 0.f, 0.f, 0.f};

    const int p = tid;                     // staging chunk index base
    const int srowp = p >> 3;              // 0..31 within each 256-chunk group
    const int sch = p & 7;

    for (int k0 = 0; k0 < 1024; k0 += 64) {
        __syncthreads();
        #pragma unroll
        for (int it = 0; it < 4; ++it) {
            int row = (it << 5) + srowp;             // 0..127
            int gch = sch ^ (row & 7);               // pre-swizzled source chunk
            const unsigned short* ga = Abf + (m0 + row) * 1024 + k0 + gch * 8;
            const unsigned short* gw = WT + (n0 + row) * 1024 + k0 + gch * 8;
            gload16(ga, (const unsigned short*)(As + ((it << 8) + (wave << 6)) * 16));
            gload16(gw, (const unsigned short*)(Bs + ((it << 8) + (wave << 6)) * 16));
        }
        __syncthreads();
        #pragma unroll
        for (int ks = 0; ks < 2; ++ks) {
            bf16x8 af[4], bfr[4];
            #pragma unroll
            for (int m = 0; m < 4; m++) {
                int row = 64 * wr + 16 * m + l15;
                af[m] = *(const bf16x8*)(As + row * 128 + (((ks << 2) | lg) ^ (row & 7)) * 16);
            }
            #pragma unroll
            for (int n = 0; n < 4; n++) {
                int row = 64 * wc + 16 * n + l15;
                bfr[n] = *(const bf16x8*)(Bs + row * 128 + (((ks << 2) | lg) ^ (row & 7)) * 16);
            }
            #pragma unroll
            for (int m = 0; m < 4; m++)
                #pragma unroll
                for (int n = 0; n < 4; n++) acc[m][n] = mfma16(af[m], bfr[n], acc[m][n]);
        }
    }

    const int rowbase = m0 + 64 * wr + 4 * lg;  // + 16*m + r
    const int colbase = n0 + 64 * wc + l15;     // + 16*n
    #pragma unroll
    for (int n = 0; n < 4; n++) {
        int col = colbase + 16 * n;
        float bias = ball[col];
        if (col < 2048) {                       // q or k with RoPE
            bool isK = col >= 1024;
            int c = col & 1023;
            int hh = c >> 6, d = c & 63;
            unsigned short* dst = isK ? kb : qb;
            #pragma unroll
            for (int m = 0; m < 4; m++) {
                float resv[4];
                #pragma unroll
                for (int r = 0; r < 4; r++) {
                    int row = rowbase + 16 * m + r;
                    int s = row & (SEQ - 1);
                    int bsel = row >> 11;
                    float v = acc[m][n][r] + bias;
                    if (isK) v *= 0.125f;
                    float cs = rcos[s * 64 + d], sn = rsin[s * 64 + d];
                    float pv = __shfl_xor(v, 1);
                    float res = ((d & 1) == 0) ? (v * cs - pv * sn) : (v * cs + pv * sn);
                    resv[r] = res;
                    float pr = __shfl_xor(res, 1);
                    if ((lane & 1) == 0) {
                        unsigned int pk = (unsigned int)f2bf(res) | ((unsigned int)f2bf(pr) << 16);
                        *(unsigned int*)&dst[(((bsel * NH + hh) * SEQ) + s) * KHD + d] = pk;
                    }
                }
                if (isK) {                       // transposed K copy (b,h,kd,s)
                    int row0 = rowbase + 16 * m;
                    int s0 = row0 & (SEQ - 1);
                    int bsel = row0 >> 11;
                    ushort4 u4;
                    u4.x = f2bf(resv[0]); u4.y = f2bf(resv[1]);
                    u4.z = f2bf(resv[2]); u4.w = f2bf(resv[3]);
                    *(ushort4*)&kbT[(((bsel * NH + hh) * KHD) + d) * SEQ + s0] = u4;
                }
            }
        } else if (col < 4096) {                // v -> transposed (b,h,vd,s)
            int c = col - 2048;
            int hh = c >> 7, vd = c & 127;
            #pragma unroll
            for (int m = 0; m < 4; m++) {
                int row = rowbase + 16 * m;
                int s = row & (SEQ - 1);
                int bsel = row >> 11;
                ushort4 u4;
                u4.x = f2bf(acc[m][n][0] + bias);
                u4.y = f2bf(acc[m][n][1] + bias);
                u4.z = f2bf(acc[m][n][2] + bias);
                u4.w = f2bf(acc[m][n][3] + bias);
                *(ushort4*)&vb[(((bsel * NH + hh) * VHD) + vd) * SEQ + s] = u4;
            }
        } else {                                // gate -> silu, (b,s,2048)
            int c = col - 4096;
            #pragma unroll
            for (int m = 0; m < 4; m++) {
                #pragma unroll
                for (int r = 0; r < 4; r++) {
                    int row = rowbase + 16 * m + r;
                    int s = row & (SEQ - 1);
                    int bsel = row >> 11;
                    float v = acc[m][n][r] + bias;
                    float sg = v / (1.f + expf(-v));
                    float pr = __shfl_xor(sg, 1);
                    if ((lane & 1) == 0) {
                        unsigned int pk = (unsigned int)f2bf(sg) | ((unsigned int)f2bf(pr) << 16);
                        *(unsigned int*)&gb[((bsel * SEQ + s) * DV) + c] = pk;
                    }
                }
            }
        }
    }
}

// ---------------- pass 1: per-chunk decay-weighted KV state
// A_c[vd,kd] = sum_{j in chunk} lambda^{64-j~} k[j,kd] v[j,vd]   (f32)
__global__ __launch_bounds__(256) void chunk_kv_kernel(
    const unsigned short* __restrict__ kbT, const unsigned short* __restrict__ vb,
    float* __restrict__ Araw) {
    __shared__ char KT[64 * 128];    // kd x s(64)
    __shared__ char VT[128 * 128];   // vd x s(64)
    const int tid = threadIdx.x, lane = tid & 63, wave = tid >> 6;
    const int l15 = lane & 15, lg = lane >> 4;
    const int c = blockIdx.x, bh = blockIdx.y;
    const int h = bh & 15;
    const float dl2 = log1pf(-exp2f(-(float)(5 + h))) * 1.44269504088896f;

    // stage K^T with decay scale lambda^{64 - s~}
    #pragma unroll
    for (int it = 0; it < 2; ++it) {
        int idx = tid + it * 256;            // 0..511
        int kd = idx >> 3, sc = (idx & 7) * 8;
        uint4 raw = *(const uint4*)(kbT + ((size_t)(bh * KHD + kd)) * SEQ + c * 64 + sc);
        unsigned short* rs = (unsigned short*)&raw;
        unsigned short outv[8];
        #pragma unroll
        for (int e = 0; e < 8; ++e)
            outv[e] = f2bf(bf2f(rs[e]) * exp2f((float)(64 - (sc + e)) * dl2));
        *(uint4*)(KT + swz(kd, sc * 2)) = *(uint4*)outv;
    }
    // stage V^T
    #pragma unroll
    for (int it = 0; it < 4; ++it) {
        int idx = tid + it * 256;            // 0..1023
        int vd = idx >> 3, sc = (idx & 7) * 8;
        uint4 raw = *(const uint4*)(vb + ((size_t)(bh * VHD + vd)) * SEQ + c * 64 + sc);
        *(uint4*)(VT + swz(vd, sc * 2)) = raw;
    }
    __syncthreads();

    f32x4 acc[2][4];
    #pragma unroll
    for (int m = 0; m < 2; m++)
        #pragma unroll
        for (int n = 0; n < 4; n++) acc[m][n] = (f32x4){0.f, 0.f, 0.f, 0.f};

    #pragma unroll
    for (int k = 0; k < 2; k++) {
        int colb = 64 * k + 16 * lg;
        bf16x8 af[2], bfr[4];
        #pragma unroll
        for (int m = 0; m < 2; m++) af[m] = *(const bf16x8*)(VT + swz(32 * wave + 16 * m + l15, colb));
        #pragma unroll
        for (int n = 0; n < 4; n++) bfr[n] = *(const bf16x8*)(KT + swz(16 * n + l15, colb));
        #pragma unroll
        for (int m = 0; m < 2; m++)
            #pragma unroll
            for (int n = 0; n < 4; n++) acc[m][n] = mfma16(af[m], bfr[n], acc[m][n]);
    }

    float* base = Araw + ((size_t)(bh * NCHUNK + c)) * (VHD * KHD);
    #pragma unroll
    for (int m = 0; m < 2; m++)
        #pragma unroll
        for (int n = 0; n < 4; n++) {
            int col = 16 * n + l15;
            #pragma unroll
            for (int r = 0; r < 4; r++) {
                int row = 32 * wave + 16 * m + 4 * lg + r;
                base[row * KHD + col] = acc[m][n][r];
            }
        }
}

// ---------------- pass 2: scan  S_{t+1} = lambda^64 * S_t + A_t ; state[t] = S_t (bf16)
__global__ __launch_bounds__(256) void scan_kernel(
    const float* __restrict__ Araw, unsigned short* __restrict__ state) {
    const int slice = blockIdx.x, bh = blockIdx.y;
    const int h = bh & 15;
    const float dl2 = log1pf(-exp2f(-(float)(5 + h))) * 1.44269504088896f;
    const float l64 = exp2f(64.f * dl2);
    const int elem = slice * 1024 + threadIdx.x * 4;

    float4 S = {0.f, 0.f, 0.f, 0.f};
    float4 a = *(const float4*)&Araw[((size_t)(bh * NCHUNK)) * 8192 + elem];
    #pragma unroll 4
    for (int t = 0; t < NCHUNK; ++t) {
        float4 an;
        if (t < NCHUNK - 1)
            an = *(const float4*)&Araw[((size_t)(bh * NCHUNK + t + 1)) * 8192 + elem];
        ushort4 o;
        o.x = f2bf(S.x); o.y = f2bf(S.y); o.z = f2bf(S.z); o.w = f2bf(S.w);
        *(ushort4*)&state[((size_t)(bh * NCHUNK + t)) * 8192 + elem] = o;
        S.x = l64 * S.x + a.x; S.y = l64 * S.y + a.y;
        S.z = l64 * S.z + a.z; S.w = l64 * S.w + a.w;
        a = an;
    }
}

// ---------------- pass 3: O[i] = intra(diag tile) + lambda^{i~} * q_i . S_t
// then per-row LN over VD, * silu(gate), write z
__global__ __launch_bounds__(256) void retention2_kernel(
    const unsigned short* __restrict__ qb, const unsigned short* __restrict__ kb,
    const unsigned short* __restrict__ vb, const unsigned short* __restrict__ state,
    const unsigned short* __restrict__ gb, const float* __restrict__ lng,
    const float* __restrict__ lnb, unsigned short* __restrict__ zb) {
    __shared__ char Kb[64 * 128];
    __shared__ char Pb[64 * 128];
    __shared__ char Vb[128 * 128];
    __shared__ char Sb[128 * 128];
    const int tid = threadIdx.x, lane = tid & 63, wave = tid >> 6;
    const int l15 = lane & 15, lg = lane >> 4;
    const int itile = blockIdx.x, bh = blockIdx.y;
    const int b = bh >> 4, h = bh & 15;
    const int i0 = itile * 64;
    const float dl2 = log1pf(-exp2f(-(float)(5 + h))) * 1.44269504088896f;

    const int srow = tid >> 3, scolb = (tid & 7) * 16;

    {   // stage K (s,kd)
        const unsigned short* kbase = kb + (bh * SEQ + i0) * KHD;
        uint4 k0 = *(const uint4*)(kbase + tid * 8);
        uint4 k1 = *(const uint4*)(kbase + tid * 8 + 2048);
        *(uint4*)(Kb + swz(srow, scolb)) = k0;
        *(uint4*)(Kb + swz(srow + 32, scolb)) = k1;
        // stage V^T (vd, s)
        const unsigned short* vbase = vb + (size_t)bh * VHD * SEQ;
        #pragma unroll
        for (int it = 0; it < 4; ++it) {
            int o = tid * 8 + it * 2048;
            uint4 vv = *(const uint4*)(vbase + (o >> 6) * SEQ + i0 + (o & 63));
            *(uint4*)(Vb + swz(o >> 6, (o & 63) * 2)) = vv;
        }
        // stage S_t (vd, kd) bf16
        const unsigned short* sbase = state + ((size_t)(bh * NCHUNK + itile)) * 8192;
        #pragma unroll
        for (int it = 0; it < 4; ++it) {
            int o = tid * 8 + it * 2048;
            uint4 sv = *(const uint4*)(sbase + o);
            *(uint4*)(Sb + swz(o >> 6, (o & 63) * 2)) = sv;
        }
    }
    // Q fragments straight from global (L2-resident, each used many times in-reg)
    const unsigned short* qrow = qb + (bh * SEQ + i0 + 16 * wave + l15) * KHD;
    bf16x8 aq0 = *(const bf16x8*)(qrow + 8 * lg);
    bf16x8 aq1 = *(const bf16x8*)(qrow + 32 + 8 * lg);
    __syncthreads();

    // diagonal decay factors lambda^{il-jl} masked
    float based[4][4];
    #pragma unroll
    for (int n = 0; n < 4; n++)
        #pragma unroll
        for (int r = 0; r < 4; r++) {
            int d = (4 * lg + r) - (16 * n + l15) + 16 * wave;
            based[n][r] = (d >= 0) ? exp2f((float)d * dl2) : 0.f;
        }

    // intra: QK^T on diagonal tile
    f32x4 pacc[4];
    #pragma unroll
    for (int n = 0; n < 4; n++) pacc[n] = (f32x4){0.f, 0.f, 0.f, 0.f};
    #pragma unroll
    for (int n = 0; n < 4; n++) {
        bf16x8 b0 = *(const bf16x8*)(Kb + swz(16 * n + l15, 16 * lg));
        bf16x8 b1 = *(const bf16x8*)(Kb + swz(16 * n + l15, 64 + 16 * lg));
        pacc[n] = mfma16(aq0, b0, pacc[n]);
        pacc[n] = mfma16(aq1, b1, pacc[n]);
    }
    #pragma unroll
    for (int n = 0; n < 4; n++)
        #pragma unroll
        for (int r = 0; r < 4; r++) {
            int il = 16 * wave + 4 * lg + r;
            int jl = 16 * n + l15;
            *(unsigned short*)(Pb + swz(il, jl * 2)) = f2bf(pacc[n][r] * based[n][r]);
        }
    bf16x8 ap0 = *(const bf16x8*)(Pb + swz(16 * wave + l15, 16 * lg));
    bf16x8 ap1 = *(const bf16x8*)(Pb + swz(16 * wave + l15, 64 + 16 * lg));

    f32x4 oacc[8], cacc[8];
    #pragma unroll
    for (int n = 0; n < 8; n++) {
        oacc[n] = (f32x4){0.f, 0.f, 0.f, 0.f};
        cacc[n] = (f32x4){0.f, 0.f, 0.f, 0.f};
    }
    #pragma unroll
    for (int n = 0; n < 8; n++) {
        bf16x8 b0 = *(const bf16x8*)(Vb + swz(16 * n + l15, 16 * lg));
        bf16x8 b1 = *(const bf16x8*)(Vb + swz(16 * n + l15, 64 + 16 * lg));
        oacc[n] = mfma16(ap0, b0, oacc[n]);
        oacc[n] = mfma16(ap1, b1, oacc[n]);
        bf16x8 s0 = *(const bf16x8*)(Sb + swz(16 * n + l15, 16 * lg));
        bf16x8 s1 = *(const bf16x8*)(Sb + swz(16 * n + l15, 64 + 16 * lg));
        cacc[n] = mfma16(aq0, s0, cacc[n]);
        cacc[n] = mfma16(aq1, s1, cacc[n]);
    }

    // combine, LN over 128, silu(gate), store
    #pragma unroll
    for (int r = 0; r < 4; r++) {
        int il = 16 * wave + 4 * lg + r;
        float lamI = exp2f((float)il * dl2);
        float ov[8];
        float s1 = 0.f, s2 = 0.f;
        #pragma unroll
        for (int n = 0; n < 8; n++) {
            float v = oacc[n][r] + lamI * cacc[n][r];
            ov[n] = v; s1 += v; s2 += v * v;
        }
        #pragma unroll
        for (int off = 1; off < 16; off <<= 1) { s1 += __shfl_xor(s1, off); s2 += __shfl_xor(s2, off); }
        float mean = s1 * (1.f / 128.f);
        float var = s2 * (1.f / 128.f) - mean * mean;
        float rstd = rsqrtf(var + 1e-5f);
        int s = i0 + il;
        int zrow = b * SEQ + s;
        #pragma unroll
        for (int n = 0; n < 8; n++) {
            int col = 16 * n + l15;
            float y = (ov[n] - mean) * rstd * lng[col] + lnb[col];
            float g = bf2f(gb[zrow * DV + h * VHD + col]);
            zb[zrow * DV + h * VHD + col] = f2bf(y * g);
        }
    }
}

// ---------------- GEMM2: z[4096x2048] @ WoT[1024x2048]^T + bo -> out f32
__global__ __launch_bounds__(256) void gemm2_kernel(
    const unsigned short* __restrict__ Z, const unsigned short* __restrict__ WoT,
    const float* __restrict__ bo, float* __restrict__ out) {
    __shared__ char As[128 * 128];
    __shared__ char Bs[128 * 128];
    const int tid = threadIdx.x;
    const int lane = tid & 63, wave = tid >> 6;
    const int wr = wave >> 1, wc = wave & 1;
    const int m0 = blockIdx.y * 128, n0 = blockIdx.x * 128;
    const int l15 = lane & 15, lg = lane >> 4;

    f32x4 acc[4][4];
    #pragma unroll
    for (int i = 0; i < 4; i++)
        #pragma unroll
        for (int j = 0; j < 4; j++) acc[i][j] = (f32x4){0.f, 0.f, 0.f, 0.f};

    const int srowp = tid >> 3, sch = tid & 7;

    for (int k0 = 0; k0 < 2048; k0 += 64) {
        __syncthreads();
        #pragma unroll
        for (int it = 0; it < 4; ++it) {
            int row = (it << 5) + srowp;
            int gch = sch ^ (row & 7);
            const unsigned short* ga = Z + (m0 + row) * 2048 + k0 + gch * 8;
            const unsigned short* gw = WoT + (n0 + row) * 2048 + k0 + gch * 8;
            gload16(ga, (const unsigned short*)(As + ((it << 8) + (wave << 6)) * 16));
            gload16(gw, (const unsigned short*)(Bs + ((it << 8) + (wave << 6)) * 16));
        }
        __syncthreads();
        #pragma unroll
        for (int ks = 0; ks < 2; ++ks) {
            bf16x8 af[4], bfr[4];
            #pragma unroll
            for (int m = 0; m < 4; m++) {
                int row = 64 * wr + 16 * m + l15;
                af[m] = *(const bf16x8*)(As + row * 128 + (((ks << 2) | lg) ^ (row & 7)) * 16);
            }
            #pragma unroll
            for (int n = 0; n < 4; n++) {
                int row = 64 * wc + 16 * n + l15;
                bfr[n] = *(const bf16x8*)(Bs + row * 128 + (((ks << 2) | lg) ^ (row & 7)) * 16);
            }
            #pragma unroll
            for (int m = 0; m < 4; m++)
                #pragma unroll
                for (int n = 0; n < 4; n++) acc[m][n] = mfma16(af[m], bfr[n], acc[m][n]);
        }
    }

    #pragma unroll
    for (int n = 0; n < 4; n++) {
        int col = n0 + 64 * wc + 16 * n + l15;
        float bias = bo[col];
        #pragma unroll
        for (int m = 0; m < 4; m++) {
            #pragma unroll
            for (int r = 0; r < 4; r++) {
                int row = m0 + 64 * wr + 16 * m + 4 * lg + r;
                out[row * 1024 + col] = acc[m][n][r] + bias;
            }
        }
    }
}

extern "C" void kernel_launch(void* const* d_in, const int* in_sizes, int n_in,
                              void* d_out, int out_size, void* d_ws, size_t ws_size,
                              hipStream_t stream) {
    (void)in_sizes; (void)n_in; (void)out_size; (void)ws_size;
    const float* x   = (const float*)d_in[0];
    const float* Wq  = (const float*)d_in[2];
    const float* bq  = (const float*)d_in[3];
    const float* Wk  = (const float*)d_in[4];
    const float* bk  = (const float*)d_in[5];
    const float* Wv  = (const float*)d_in[6];
    const float* bv  = (const float*)d_in[7];
    const float* Wg  = (const float*)d_in[8];
    const float* bg  = (const float*)d_in[9];
    const float* Wo  = (const float*)d_in[10];
    const float* bo  = (const float*)d_in[11];
    const float* lpg = (const float*)d_in[12];
    const float* lpb = (const float*)d_in[13];
    const float* lhg = (const float*)d_in[14];
    const float* lhb = (const float*)d_in[15];

    char* w = (char*)d_ws;
    auto alloc = [&](size_t bytes) { char* p = w; w += (bytes + 255) & ~(size_t)255; return p; };
    unsigned short* WT    = (unsigned short*)alloc((size_t)N1 * DIM * 2);
    unsigned short* WoT   = (unsigned short*)alloc((size_t)DIM * DV * 2);
    float*          ball  = (float*)alloc((size_t)N1 * 4);
    float*          rsin  = (float*)alloc((size_t)SEQ * 64 * 4);
    float*          rcos  = (float*)alloc((size_t)SEQ * 64 * 4);
    unsigned short* xn    = (unsigned short*)alloc((size_t)MROWS * DIM * 2);
    unsigned short* qb    = (unsigned short*)alloc((size_t)BATCH * NH * SEQ * KHD * 2);
    unsigned short* kb    = (unsigned short*)alloc((size_t)BATCH * NH * SEQ * KHD * 2);
    unsigned short* kbT   = (unsigned short*)alloc((size_t)BATCH * NH * KHD * SEQ * 2);
    unsigned short* vb    = (unsigned short*)alloc((size_t)BATCH * NH * VHD * SEQ * 2);
    unsigned short* gb    = (unsigned short*)alloc((size_t)MROWS * DV * 2);
    unsigned short* zb    = (unsigned short*)alloc((size_t)MROWS * DV * 2);
    float*          Araw  = (float*)alloc((size_t)BATCH * NH * NCHUNK * VHD * KHD * 4);
    unsigned short* stateb= (unsigned short*)alloc((size_t)BATCH * NH * NCHUNK * VHD * KHD * 2);

    dim3 tb(32, 8);
    transpose_cvt<<<dim3(32, 32), tb, 0, stream>>>(Wq, WT + 0 * DIM, DIM, DIM);
    transpose_cvt<<<dim3(32, 32), tb, 0, stream>>>(Wk, WT + 1024 * DIM, DIM, DIM);
    transpose_cvt<<<dim3(64, 32), tb, 0, stream>>>(Wv, WT + 2048 * DIM, DIM, DV);
    transpose_cvt<<<dim3(64, 32), tb, 0, stream>>>(Wg, WT + 4096 * DIM, DIM, DV);
    transpose_cvt<<<dim3(32, 64), tb, 0, stream>>>(Wo, WoT, DV, DIM);
    bias_concat<<<24, 256, 0, stream>>>(bq, bk, bv, bg, ball);
    rope_kernel<<<256, 256, 0, stream>>>(rsin, rcos);
    ln_x_kernel<<<MROWS, 256, 0, stream>>>(x, lpg, lpb, xn);
    gemm1_kernel<<<dim3(48, 32), 256, 0, stream>>>(xn, WT, ball, rsin, rcos, qb, kb, kbT, vb, gb);
    chunk_kv_kernel<<<dim3(NCHUNK, 32), 256, 0, stream>>>(kbT, vb, Araw);
    scan_kernel<<<dim3(8, 32), 256, 0, stream>>>(Araw, stateb);
    retention2_kernel<<<dim3(NCHUNK, 32), 256, 0, stream>>>(qb, kb, vb, stateb, gb, lhg, lhb, zb);
    gemm2_kernel<<<dim3(8, 32), 256, 0, stream>>>(zb, WoT, bo, (float*)d_out);
}